// Round 2
// baseline (10285.239 us; speedup 1.0000x reference)
//
#include <hip/hip_runtime.h>

// ---------------------------------------------------------------------------
// 2-layer "bidirectional" LSTM generator, B=2048, T=128, HID=150.
// Strategy: batch-partitioned persistent kernel. 64 WGs x 512 threads,
// 32 batch rows per WG, weights pre-packed to f16 MFMA A-fragments and
// streamed from L2 each step. Gates on M-axis packed 4j+{i,f,g,o} so the
// 16x16x32 C-fragment puts all 4 gates of a (j,batch) cell in one lane.
// h-state lives in LDS (B-operand), c-state in registers of owning lane.
// R1: __launch_bounds__(512,2) -> 256 VGPR cap (R0 spilled at 128: 150 MB
// scratch writes -> L2 thrash -> 63% weight-load miss). bias0 hoisted to regs.
// ---------------------------------------------------------------------------

typedef _Float16 f16;
typedef _Float16 f16x8 __attribute__((ext_vector_type(8)));
typedef _Float16 f16x4v __attribute__((ext_vector_type(4)));
typedef _Float16 f16x2v __attribute__((ext_vector_type(2)));
typedef float    f32x4 __attribute__((ext_vector_type(4)));

#define LOG2E 1.44269504f

__device__ __forceinline__ float sigm_(float x) {
    float e = __builtin_amdgcn_exp2f(-LOG2E * x);
    return __builtin_amdgcn_rcpf(1.f + e);
}
__device__ __forceinline__ float tanh_(float x) {
    float e = __builtin_amdgcn_exp2f(2.f * LOG2E * x);
    return 1.f - 2.f * __builtin_amdgcn_rcpf(1.f + e);
}

// ---------------- ws layout (bytes) ----------------
#define OFF_CINIT 2621440
#define OFF_BIAS0 7864320
#define OFF_PW0   13107200
#define OFF_PW1   13516800
#define OFF_PWPJ  14745600
#define OFF_B1P   14766080

// z[b] = [noise(100), targets(2), masks(3)]
__device__ float dot105(const float* __restrict__ noise,
                        const float* __restrict__ targ,
                        const float* __restrict__ msk,
                        const float* __restrict__ Wrow, int bb) {
    float s = 0.f;
    const float* nz = noise + (size_t)bb * 100;
#pragma unroll 4
    for (int k = 0; k < 100; ++k) s += nz[k] * Wrow[k];
    s += targ[bb*2+0]*Wrow[100] + targ[bb*2+1]*Wrow[101];
    s += msk[bb*3+0]*Wrow[102] + msk[bb*3+1]*Wrow[103] + msk[bb*3+2]*Wrow[104];
    return s;
}

// Build HINIT (tile layout [h1b | h0f,x | h0b,x | h1f], regions of 160) and CINIT.
// Replicates torch's (B,1200).view(8,B,150) on the row-major init-matmul buffer.
__global__ void k_init(const float* __restrict__ noise, const float* __restrict__ targ,
                       const float* __restrict__ msk,
                       const float* __restrict__ Wih, const float* __restrict__ bih,
                       const float* __restrict__ Wtk, const float* __restrict__ btk,
                       f16* __restrict__ hinit, float* __restrict__ cinitp) {
    int gid = blockIdx.x * 256 + threadIdx.x;   // 2048*1280 exact
    int b = gid / 1280, c = gid % 1280;
    if (c < 640) {
        int reg = c / 160, loc = c % 160;
        float v = 0.f; bool has = false;
        if (loc < 150) {
            int q = (reg == 0) ? 3 : (reg == 1) ? 0 : (reg == 2) ? 1 : 2; // h1b,h0f,h0b,h1f
            size_t i = (size_t)q * 2048 * 150 + (size_t)b * 150 + loc;
            int bb = (int)(i / 1200), rr = (int)(i % 1200);
            v = dot105(noise, targ, msk, Wih + (size_t)rr * 105, bb) + bih[rr];
            has = true;
        } else if (loc < 152 && (reg == 1 || reg == 2)) {
            int o = loc - 150;
            v = dot105(noise, targ, msk, Wtk + o * 105, b) + btk[o];
            has = true;
        }
        hinit[(size_t)b * 640 + c] = has ? (f16)v : (f16)0.f;
    } else {
        int idx = c - 640;                       // layer*320 + d*160 + j
        int layer = idx / 320, r = idx % 320, d = r / 160, j = r % 160;
        float v = 0.f;
        if (j < 150) {
            int q = 4 + layer * 2 + d;
            size_t i = (size_t)q * 2048 * 150 + (size_t)b * 150 + j;
            int bb = (int)(i / 1200), rr = (int)(i % 1200);
            v = dot105(noise, targ, msk, Wih + (size_t)rr * 105, bb) + bih[rr];
        }
        cinitp[(((size_t)layer * 2048 + b) * 2 + d) * 160 + j] = v;
    }
}

// Pack weights into MFMA A-fragment order. A-frag lane l holds
// A[row=l&15][k=(l>>4)*8+e]. M-row r16 -> j=jt*4+(r16>>2), gate g=r16&3.
__global__ void k_pack(const float* __restrict__ Wih0, const float* __restrict__ Whh0,
                       const float* __restrict__ Wih1, const float* __restrict__ Whh1,
                       const float* __restrict__ Wp,   const float* __restrict__ bl1,
                       f16* __restrict__ pw0, f16* __restrict__ pw1,
                       f16* __restrict__ pwpj, f16* __restrict__ b1p) {
    int gid = blockIdx.x * 256 + threadIdx.x;
    const int N0 = 80*5*512, N1 = 80*15*512, NP = 20*512;
    if (gid < N0) {
        int e = gid & 7, l = (gid >> 3) & 63, f = gid >> 9;
        int ks = f % 5, mt = f / 5;
        int d = mt / 40, jt = mt % 40, r16 = l & 15;
        int j = jt * 4 + (r16 >> 2), g = r16 & 3;
        int k = ks * 32 + (l >> 4) * 8 + e;
        float v = 0.f;
        if (j < 150) {
            int R = d * 600 + g * 150 + j;
            if (k < 150)      v = Whh0[(size_t)R * 150 + k];
            else if (k < 152) v = Wih0[(size_t)R * 7 + (k - 150)];
        }
        pw0[gid] = (f16)v;  return;
    }
    gid -= N0;
    if (gid < N1) {
        int e = gid & 7, l = (gid >> 3) & 63, f = gid >> 9;
        int ks = f % 15, mt = f / 15;
        int d = mt / 40, jt = mt % 40, r16 = l & 15;
        int j = jt * 4 + (r16 >> 2), g = r16 & 3;
        int k = ks * 32 + (l >> 4) * 8 + e;
        float v = 0.f;
        if (j < 150) {
            int R = d * 600 + g * 150 + j;
            if (d == 0) { // window [h0f,pad | h0b,pad | h1f,pad]
                if (k < 150)                 v = Wih1[(size_t)R * 300 + k];
                else if (k >= 160 && k < 310) v = Wih1[(size_t)R * 300 + (k - 10)];
                else if (k >= 320 && k < 470) v = Whh1[(size_t)R * 150 + (k - 320)];
            } else {      // window [h1b,pad | h0f,pad | h0b,pad]
                if (k < 150)                 v = Whh1[(size_t)R * 150 + k];
                else if (k >= 160 && k < 310) v = Wih1[(size_t)R * 300 + (k - 160)];
                else if (k >= 320 && k < 470) v = Wih1[(size_t)R * 300 + (k - 170)];
            }
        }
        pw1[gid] = (f16)v;  return;
    }
    gid -= N1;
    if (gid < NP) {
        int e = gid & 7, l = (gid >> 3) & 63, ks = gid >> 9;
        int r16 = l & 15;
        int k = ks * 32 + (l >> 4) * 8 + e;
        float v = 0.f;
        if (r16 < 2) {  // whole-tile window: h1b at cols 0..149, h1f at 480..629
            if (k < 150)                  v = Wp[r16 * 300 + 150 + k];
            else if (k >= 480 && k < 630) v = Wp[r16 * 300 + (k - 480)];
        }
        pwpj[gid] = (f16)v;  return;
    }
    gid -= NP;
    {   // b_l1 gate-packed: [mt][r16]
        int r16 = gid & 15, mt = gid >> 4;
        int d = mt / 40, jt = mt % 40;
        int j = jt * 4 + (r16 >> 2), g = r16 & 3;
        float v = (j < 150) ? bl1[d * 600 + g * 150 + j] : 0.f;
        b1p[gid] = (f16)v;
    }
}

// bias0[b][d][j][g] = b_l0 + Wih_l0[:,:,2:7] @ y[b]   (time-invariant L0 input part)
__global__ void k_bias0(const float* __restrict__ Wih0, const float* __restrict__ bl0,
                        const float* __restrict__ targ, const float* __restrict__ msk,
                        f16* __restrict__ bias0) {
    int gid = blockIdx.x * 256 + threadIdx.x;  // 2048*1280 exact
    int b = gid / 1280, r = gid % 1280;
    int d = r / 640, s = r % 640, j = s >> 2, g = s & 3;
    float v = 0.f;
    if (j < 150) {
        int R = d * 600 + g * 150 + j;
        const float* wr = Wih0 + (size_t)R * 7;
        v = bl0[R] + wr[2]*targ[b*2+0] + wr[3]*targ[b*2+1]
                   + wr[4]*msk[b*3+0] + wr[5]*msk[b*3+1] + wr[6]*msk[b*3+2];
    }
    bias0[gid] = (f16)v;
}

// ---------------------------------------------------------------------------
// Main persistent kernel: 64 WGs x 512 thr (8 waves), 32 batch rows per WG.
// Waves 0-3: fwd dir (Mt 0..39), waves 4-7: bwd (Mt 40..79); 10 M-tiles/wave.
// Tile cols: [0:h1b | 160:h0f(+x@150,151) | 320:h0b(+x) | 480:h1f], stride 656 f16.
// __launch_bounds__(512,2): 2 waves/SIMD -> 256 VGPR cap (R0: 128 cap spilled).
// ---------------------------------------------------------------------------
__global__ __launch_bounds__(512, 2) void lstm_main(
    const f16* __restrict__ hinit, const float* __restrict__ cinit,
    const f16* __restrict__ bias0, const f16* __restrict__ pw0,
    const f16* __restrict__ pw1,   const f16* __restrict__ pwpj,
    const f16* __restrict__ b1p,   const float* __restrict__ bproj,
    const int* __restrict__ lengths, float* __restrict__ out) {
    __shared__ f16 tile[32 * 656];
    const int tid = threadIdx.x;
    const int w = tid >> 6, l = tid & 63;
    const int wg = blockIdx.x, b0 = wg * 32;
    const int l15 = l & 15, lg = l >> 4;

    // stage initial h/x into LDS tile (XOR-swizzled rows)
    for (int it = tid; it < 32 * 80; it += 512) {
        int row = it / 80, c8 = (it % 80) * 8;
        f16x8 v = *(const f16x8*)(hinit + (size_t)(b0 + row) * 640 + c8);
        int byte = row * 1312 + c8 * 2;  byte ^= (row & 7) << 4;
        *(f16x8*)((char*)tile + byte) = v;
    }

    const int dirw = w >> 2;
    int jj[10];
#pragma unroll
    for (int m = 0; m < 10; ++m) jj[m] = ((w * 10 + m) % 40) * 4 + lg;

    float c0s[10][2], c1s[10][2];
#pragma unroll
    for (int m = 0; m < 10; ++m)
#pragma unroll
        for (int nt = 0; nt < 2; ++nt) {
            int b = b0 + nt * 16 + l15;
            c0s[m][nt] = cinit[(((size_t)b) * 2 + dirw) * 160 + jj[m]];
            c1s[m][nt] = cinit[(((size_t)2048 + b) * 2 + dirw) * 160 + jj[m]];
        }

    f16x4v b1v[10];
#pragma unroll
    for (int m = 0; m < 10; ++m)
        b1v[m] = *(const f16x4v*)(b1p + (w * 10 + m) * 16 + lg * 4);

    // hoisted time-invariant L0 bias (R1): 10m x 2nt x f16x4 = 40 VGPRs,
    // removes 20 global loads/wave/step.
    f16x4v bz0[10][2];
#pragma unroll
    for (int m = 0; m < 10; ++m)
#pragma unroll
        for (int nt = 0; nt < 2; ++nt) {
            int b = b0 + nt * 16 + l15;
            bz0[m][nt] = *(const f16x4v*)(bias0 + (size_t)b * 1280 + dirw * 640 + jj[m] * 4);
        }

    const float bp0 = bproj[0], bp1 = bproj[1];
    int lenb = 0;
    if (w < 2 && l < 16) lenb = lengths[b0 + w * 16 + l];

    const int baseL0 = 160 + dirw * 160;
    const int baseL1 = dirw ? 0 : 160;
    const int hw1    = dirw ? 0 : 480;

    __syncthreads();

    for (int t = 0; t < 128; ++t) {
        f32x4 acc[10][2];
        // ---- Phase A: L0 GEMM (K=160: h0_d + x + pad) ----
#pragma unroll
        for (int m = 0; m < 10; ++m)
#pragma unroll
            for (int nt = 0; nt < 2; ++nt) {
                f16x4v bz = bz0[m][nt];
                acc[m][nt] = (f32x4){(float)bz[0], (float)bz[1], (float)bz[2], (float)bz[3]};
            }
#pragma unroll
        for (int ks = 0; ks < 5; ++ks) {
            f16x8 bf[2];
#pragma unroll
            for (int nt = 0; nt < 2; ++nt) {
                int row = nt * 16 + l15;
                int byte = row * 1312 + (baseL0 + ks * 32 + lg * 8) * 2;  byte ^= (row & 7) << 4;
                bf[nt] = *(const f16x8*)((const char*)tile + byte);
            }
#pragma unroll
            for (int m = 0; m < 10; ++m) {
                f16x8 a = *(const f16x8*)(pw0 + (((size_t)(w * 10 + m) * 5 + ks) * 64 + l) * 8);
                acc[m][0] = __builtin_amdgcn_mfma_f32_16x16x32_f16(a, bf[0], acc[m][0], 0, 0, 0);
                acc[m][1] = __builtin_amdgcn_mfma_f32_16x16x32_f16(a, bf[1], acc[m][1], 0, 0, 0);
            }
        }
        __syncthreads();
        // ---- Phase B: act0 -> h0 into tile ----
#pragma unroll
        for (int m = 0; m < 10; ++m)
#pragma unroll
            for (int nt = 0; nt < 2; ++nt) {
                float gi = sigm_(acc[m][nt][0]);
                float gf = sigm_(acc[m][nt][1]);
                float gg = tanh_(acc[m][nt][2]);
                float go = sigm_(acc[m][nt][3]);
                float c = gf * c0s[m][nt] + gi * gg;
                c0s[m][nt] = c;
                float h = go * tanh_(c);
                if (jj[m] < 150) {
                    int row = nt * 16 + l15;
                    int byte = row * 1312 + (baseL0 + jj[m]) * 2;  byte ^= (row & 7) << 4;
                    *(f16*)((char*)tile + byte) = (f16)h;
                }
            }
        __syncthreads();
        // ---- Phase C: L1 GEMM (K=480) ----
#pragma unroll
        for (int m = 0; m < 10; ++m) {
            f32x4 bi = (f32x4){(float)b1v[m][0], (float)b1v[m][1], (float)b1v[m][2], (float)b1v[m][3]};
            acc[m][0] = bi;  acc[m][1] = bi;
        }
#pragma unroll
        for (int ks = 0; ks < 15; ++ks) {
            f16x8 bf[2];
#pragma unroll
            for (int nt = 0; nt < 2; ++nt) {
                int row = nt * 16 + l15;
                int byte = row * 1312 + (baseL1 + ks * 32 + lg * 8) * 2;  byte ^= (row & 7) << 4;
                bf[nt] = *(const f16x8*)((const char*)tile + byte);
            }
#pragma unroll
            for (int m = 0; m < 10; ++m) {
                f16x8 a = *(const f16x8*)(pw1 + (((size_t)(w * 10 + m) * 15 + ks) * 64 + l) * 8);
                acc[m][0] = __builtin_amdgcn_mfma_f32_16x16x32_f16(a, bf[0], acc[m][0], 0, 0, 0);
                acc[m][1] = __builtin_amdgcn_mfma_f32_16x16x32_f16(a, bf[1], acc[m][1], 0, 0, 0);
            }
        }
        __syncthreads();
        // ---- Phase D: act1 -> h1 into tile ----
#pragma unroll
        for (int m = 0; m < 10; ++m)
#pragma unroll
            for (int nt = 0; nt < 2; ++nt) {
                float gi = sigm_(acc[m][nt][0]);
                float gf = sigm_(acc[m][nt][1]);
                float gg = tanh_(acc[m][nt][2]);
                float go = sigm_(acc[m][nt][3]);
                float c = gf * c1s[m][nt] + gi * gg;
                c1s[m][nt] = c;
                float h = go * tanh_(c);
                if (jj[m] < 150) {
                    int row = nt * 16 + l15;
                    int byte = row * 1312 + (hw1 + jj[m]) * 2;  byte ^= (row & 7) << 4;
                    *(f16*)((char*)tile + byte) = (f16)h;
                }
            }
        __syncthreads();
        // ---- Phase E: proj + output + x writeback (waves 0,1) ----
        if (w < 2) {
            f32x4 ap = (f32x4){0.f, 0.f, 0.f, 0.f};
#pragma unroll
            for (int ks = 0; ks < 20; ++ks) {
                int row = w * 16 + l15;
                int byte = row * 1312 + (ks * 32 + lg * 8) * 2;  byte ^= (row & 7) << 4;
                f16x8 bfp = *(const f16x8*)((const char*)tile + byte);
                f16x8 a = *(const f16x8*)(pwpj + ((size_t)ks * 64 + l) * 8);
                ap = __builtin_amdgcn_mfma_f32_16x16x32_f16(a, bfp, ap, 0, 0, 0);
            }
            if (l < 16) {
                float o0 = ap[0] + bp0, o1 = ap[1] + bp1;
                int b = b0 + w * 16 + l;
                bool live = (t < lenb);
                *(float2*)(out + ((size_t)b * 128 + t) * 2) =
                    make_float2(live ? o0 : 0.f, live ? o1 : 0.f);
                int row = w * 16 + l;
                f16x2v xv = {(f16)o0, (f16)o1};
                int byte1 = row * 1312 + 620;  byte1 ^= (row & 7) << 4;   // h0f x cols
                *(f16x2v*)((char*)tile + byte1) = xv;
                int byte2 = row * 1312 + 940;  byte2 ^= (row & 7) << 4;   // h0b x cols
                *(f16x2v*)((char*)tile + byte2) = xv;
            }
        }
        __syncthreads();
    }
}

extern "C" void kernel_launch(void* const* d_in, const int* in_sizes, int n_in,
                              void* d_out, int out_size, void* d_ws, size_t ws_size,
                              hipStream_t stream) {
    const float* noise = (const float*)d_in[0];
    const float* targ  = (const float*)d_in[1];
    const float* msk   = (const float*)d_in[2];
    const int*   lens  = (const int*)d_in[3];
    const float* Wih0  = (const float*)d_in[5];
    const float* Whh0  = (const float*)d_in[6];
    const float* bl0   = (const float*)d_in[7];
    const float* Wih1  = (const float*)d_in[8];
    const float* Whh1  = (const float*)d_in[9];
    const float* bl1   = (const float*)d_in[10];
    const float* Wp    = (const float*)d_in[11];
    const float* bpj   = (const float*)d_in[12];
    const float* Wit   = (const float*)d_in[13];
    const float* bit   = (const float*)d_in[14];
    const float* Wtk   = (const float*)d_in[15];
    const float* btk   = (const float*)d_in[16];

    char* ws = (char*)d_ws;
    f16*   HINIT = (f16*)(ws);
    float* CINIT = (float*)(ws + OFF_CINIT);
    f16*   BIAS0 = (f16*)(ws + OFF_BIAS0);
    f16*   PW0   = (f16*)(ws + OFF_PW0);
    f16*   PW1   = (f16*)(ws + OFF_PW1);
    f16*   PWPJ  = (f16*)(ws + OFF_PWPJ);
    f16*   B1P   = (f16*)(ws + OFF_B1P);

    hipLaunchKernelGGL(k_init,  dim3(10240), dim3(256), 0, stream,
                       noise, targ, msk, Wit, bit, Wtk, btk, HINIT, CINIT);
    hipLaunchKernelGGL(k_pack,  dim3(3245), dim3(256), 0, stream,
                       Wih0, Whh0, Wih1, Whh1, Wp, bl1, PW0, PW1, PWPJ, B1P);
    hipLaunchKernelGGL(k_bias0, dim3(10240), dim3(256), 0, stream,
                       Wih0, bl0, targ, msk, BIAS0);
    hipLaunchKernelGGL(lstm_main, dim3(64), dim3(512), 0, stream,
                       HINIT, CINIT, BIAS0, PW0, PW1, PWPJ, B1P, bpj, lens,
                       (float*)d_out);
}

// Round 3
// 10046.915 us; speedup vs baseline: 1.0237x; 1.0237x over previous
//
#include <hip/hip_runtime.h>

// ---------------------------------------------------------------------------
// 2-layer "bidirectional" LSTM generator, B=2048, T=128, HID=150.
// Batch-partitioned persistent kernel. 64 WGs x 512 threads, 32 batch rows
// per WG, weights pre-packed to f16 MFMA A-fragments, streamed from L2 each
// step. Gates on M-axis packed 4j+{i,f,g,o}; 16x16x32 C-fragment puts all 4
// gates of a (j,batch) cell in one lane. h in LDS, c in registers.
// R2: amdgpu_waves_per_eu(2,2) -> 256 VGPR cap. R0/R1 were capped at 128
// ( __launch_bounds__ arg2 acted as blocks/CU: 2 blocks -> 4 waves/EU -> 128 )
// and spilled ~150 MB/call of scratch, thrashing L2 (8.1 GB weight misses).
// ---------------------------------------------------------------------------

typedef _Float16 f16;
typedef _Float16 f16x8 __attribute__((ext_vector_type(8)));
typedef _Float16 f16x4v __attribute__((ext_vector_type(4)));
typedef _Float16 f16x2v __attribute__((ext_vector_type(2)));
typedef float    f32x4 __attribute__((ext_vector_type(4)));

#define LOG2E 1.44269504f

__device__ __forceinline__ float sigm_(float x) {
    float e = __builtin_amdgcn_exp2f(-LOG2E * x);
    return __builtin_amdgcn_rcpf(1.f + e);
}
__device__ __forceinline__ float tanh_(float x) {
    float e = __builtin_amdgcn_exp2f(2.f * LOG2E * x);
    return 1.f - 2.f * __builtin_amdgcn_rcpf(1.f + e);
}

// ---------------- ws layout (bytes) ----------------
#define OFF_CINIT 2621440
#define OFF_BIAS0 7864320
#define OFF_PW0   13107200
#define OFF_PW1   13516800
#define OFF_PWPJ  14745600
#define OFF_B1P   14766080

// z[b] = [noise(100), targets(2), masks(3)]
__device__ float dot105(const float* __restrict__ noise,
                        const float* __restrict__ targ,
                        const float* __restrict__ msk,
                        const float* __restrict__ Wrow, int bb) {
    float s = 0.f;
    const float* nz = noise + (size_t)bb * 100;
#pragma unroll 4
    for (int k = 0; k < 100; ++k) s += nz[k] * Wrow[k];
    s += targ[bb*2+0]*Wrow[100] + targ[bb*2+1]*Wrow[101];
    s += msk[bb*3+0]*Wrow[102] + msk[bb*3+1]*Wrow[103] + msk[bb*3+2]*Wrow[104];
    return s;
}

// Build HINIT (tile layout [h1b | h0f,x | h0b,x | h1f], regions of 160) and CINIT.
// Replicates torch's (B,1200).view(8,B,150) on the row-major init-matmul buffer.
__global__ void k_init(const float* __restrict__ noise, const float* __restrict__ targ,
                       const float* __restrict__ msk,
                       const float* __restrict__ Wih, const float* __restrict__ bih,
                       const float* __restrict__ Wtk, const float* __restrict__ btk,
                       f16* __restrict__ hinit, float* __restrict__ cinitp) {
    int gid = blockIdx.x * 256 + threadIdx.x;   // 2048*1280 exact
    int b = gid / 1280, c = gid % 1280;
    if (c < 640) {
        int reg = c / 160, loc = c % 160;
        float v = 0.f; bool has = false;
        if (loc < 150) {
            int q = (reg == 0) ? 3 : (reg == 1) ? 0 : (reg == 2) ? 1 : 2; // h1b,h0f,h0b,h1f
            size_t i = (size_t)q * 2048 * 150 + (size_t)b * 150 + loc;
            int bb = (int)(i / 1200), rr = (int)(i % 1200);
            v = dot105(noise, targ, msk, Wih + (size_t)rr * 105, bb) + bih[rr];
            has = true;
        } else if (loc < 152 && (reg == 1 || reg == 2)) {
            int o = loc - 150;
            v = dot105(noise, targ, msk, Wtk + o * 105, b) + btk[o];
            has = true;
        }
        hinit[(size_t)b * 640 + c] = has ? (f16)v : (f16)0.f;
    } else {
        int idx = c - 640;                       // layer*320 + d*160 + j
        int layer = idx / 320, r = idx % 320, d = r / 160, j = r % 160;
        float v = 0.f;
        if (j < 150) {
            int q = 4 + layer * 2 + d;
            size_t i = (size_t)q * 2048 * 150 + (size_t)b * 150 + j;
            int bb = (int)(i / 1200), rr = (int)(i % 1200);
            v = dot105(noise, targ, msk, Wih + (size_t)rr * 105, bb) + bih[rr];
        }
        cinitp[(((size_t)layer * 2048 + b) * 2 + d) * 160 + j] = v;
    }
}

// Pack weights into MFMA A-fragment order. A-frag lane l holds
// A[row=l&15][k=(l>>4)*8+e]. M-row r16 -> j=jt*4+(r16>>2), gate g=r16&3.
__global__ void k_pack(const float* __restrict__ Wih0, const float* __restrict__ Whh0,
                       const float* __restrict__ Wih1, const float* __restrict__ Whh1,
                       const float* __restrict__ Wp,   const float* __restrict__ bl1,
                       f16* __restrict__ pw0, f16* __restrict__ pw1,
                       f16* __restrict__ pwpj, f16* __restrict__ b1p) {
    int gid = blockIdx.x * 256 + threadIdx.x;
    const int N0 = 80*5*512, N1 = 80*15*512, NP = 20*512;
    if (gid < N0) {
        int e = gid & 7, l = (gid >> 3) & 63, f = gid >> 9;
        int ks = f % 5, mt = f / 5;
        int d = mt / 40, jt = mt % 40, r16 = l & 15;
        int j = jt * 4 + (r16 >> 2), g = r16 & 3;
        int k = ks * 32 + (l >> 4) * 8 + e;
        float v = 0.f;
        if (j < 150) {
            int R = d * 600 + g * 150 + j;
            if (k < 150)      v = Whh0[(size_t)R * 150 + k];
            else if (k < 152) v = Wih0[(size_t)R * 7 + (k - 150)];
        }
        pw0[gid] = (f16)v;  return;
    }
    gid -= N0;
    if (gid < N1) {
        int e = gid & 7, l = (gid >> 3) & 63, f = gid >> 9;
        int ks = f % 15, mt = f / 15;
        int d = mt / 40, jt = mt % 40, r16 = l & 15;
        int j = jt * 4 + (r16 >> 2), g = r16 & 3;
        int k = ks * 32 + (l >> 4) * 8 + e;
        float v = 0.f;
        if (j < 150) {
            int R = d * 600 + g * 150 + j;
            if (d == 0) { // window [h0f,pad | h0b,pad | h1f,pad]
                if (k < 150)                 v = Wih1[(size_t)R * 300 + k];
                else if (k >= 160 && k < 310) v = Wih1[(size_t)R * 300 + (k - 10)];
                else if (k >= 320 && k < 470) v = Whh1[(size_t)R * 150 + (k - 320)];
            } else {      // window [h1b,pad | h0f,pad | h0b,pad]
                if (k < 150)                 v = Whh1[(size_t)R * 150 + k];
                else if (k >= 160 && k < 310) v = Wih1[(size_t)R * 300 + (k - 160)];
                else if (k >= 320 && k < 470) v = Wih1[(size_t)R * 300 + (k - 170)];
            }
        }
        pw1[gid] = (f16)v;  return;
    }
    gid -= N1;
    if (gid < NP) {
        int e = gid & 7, l = (gid >> 3) & 63, ks = gid >> 9;
        int r16 = l & 15;
        int k = ks * 32 + (l >> 4) * 8 + e;
        float v = 0.f;
        if (r16 < 2) {  // whole-tile window: h1b at cols 0..149, h1f at 480..629
            if (k < 150)                  v = Wp[r16 * 300 + 150 + k];
            else if (k >= 480 && k < 630) v = Wp[r16 * 300 + (k - 480)];
        }
        pwpj[gid] = (f16)v;  return;
    }
    gid -= NP;
    {   // b_l1 gate-packed: [mt][r16]
        int r16 = gid & 15, mt = gid >> 4;
        int d = mt / 40, jt = mt % 40;
        int j = jt * 4 + (r16 >> 2), g = r16 & 3;
        float v = (j < 150) ? bl1[d * 600 + g * 150 + j] : 0.f;
        b1p[gid] = (f16)v;
    }
}

// bias0[b][d][j][g] = b_l0 + Wih_l0[:,:,2:7] @ y[b]   (time-invariant L0 input part)
__global__ void k_bias0(const float* __restrict__ Wih0, const float* __restrict__ bl0,
                        const float* __restrict__ targ, const float* __restrict__ msk,
                        f16* __restrict__ bias0) {
    int gid = blockIdx.x * 256 + threadIdx.x;  // 2048*1280 exact
    int b = gid / 1280, r = gid % 1280;
    int d = r / 640, s = r % 640, j = s >> 2, g = s & 3;
    float v = 0.f;
    if (j < 150) {
        int R = d * 600 + g * 150 + j;
        const float* wr = Wih0 + (size_t)R * 7;
        v = bl0[R] + wr[2]*targ[b*2+0] + wr[3]*targ[b*2+1]
                   + wr[4]*msk[b*3+0] + wr[5]*msk[b*3+1] + wr[6]*msk[b*3+2];
    }
    bias0[gid] = (f16)v;
}

// ---------------------------------------------------------------------------
// Main persistent kernel: 64 WGs x 512 thr (8 waves), 32 batch rows per WG.
// Waves 0-3: fwd dir (Mt 0..39), waves 4-7: bwd (Mt 40..79); 10 M-tiles/wave.
// Tile cols: [0:h1b | 160:h0f(+x@150,151) | 320:h0b(+x) | 480:h1f], stride 656 f16.
// amdgpu_waves_per_eu(2,2): exactly 2 waves/SIMD -> 256 VGPR cap, no spill.
// ---------------------------------------------------------------------------
__global__ __launch_bounds__(512)
__attribute__((amdgpu_waves_per_eu(2, 2)))
void lstm_main(
    const f16* __restrict__ hinit, const float* __restrict__ cinit,
    const f16* __restrict__ bias0, const f16* __restrict__ pw0,
    const f16* __restrict__ pw1,   const f16* __restrict__ pwpj,
    const f16* __restrict__ b1p,   const float* __restrict__ bproj,
    const int* __restrict__ lengths, float* __restrict__ out) {
    __shared__ f16 tile[32 * 656];
    const int tid = threadIdx.x;
    const int w = tid >> 6, l = tid & 63;
    const int wg = blockIdx.x, b0 = wg * 32;
    const int l15 = l & 15, lg = l >> 4;

    // stage initial h/x into LDS tile (XOR-swizzled rows)
    for (int it = tid; it < 32 * 80; it += 512) {
        int row = it / 80, c8 = (it % 80) * 8;
        f16x8 v = *(const f16x8*)(hinit + (size_t)(b0 + row) * 640 + c8);
        int byte = row * 1312 + c8 * 2;  byte ^= (row & 7) << 4;
        *(f16x8*)((char*)tile + byte) = v;
    }

    const int dirw = w >> 2;
    int jj[10];
#pragma unroll
    for (int m = 0; m < 10; ++m) jj[m] = ((w * 10 + m) % 40) * 4 + lg;

    float c0s[10][2], c1s[10][2];
#pragma unroll
    for (int m = 0; m < 10; ++m)
#pragma unroll
        for (int nt = 0; nt < 2; ++nt) {
            int b = b0 + nt * 16 + l15;
            c0s[m][nt] = cinit[(((size_t)b) * 2 + dirw) * 160 + jj[m]];
            c1s[m][nt] = cinit[(((size_t)2048 + b) * 2 + dirw) * 160 + jj[m]];
        }

    f16x4v b1v[10];
#pragma unroll
    for (int m = 0; m < 10; ++m)
        b1v[m] = *(const f16x4v*)(b1p + (w * 10 + m) * 16 + lg * 4);

    // hoisted time-invariant L0 bias: 10m x 2nt x f16x4 = 20 VGPRs.
    f16x4v bz0[10][2];
#pragma unroll
    for (int m = 0; m < 10; ++m)
#pragma unroll
        for (int nt = 0; nt < 2; ++nt) {
            int b = b0 + nt * 16 + l15;
            bz0[m][nt] = *(const f16x4v*)(bias0 + (size_t)b * 1280 + dirw * 640 + jj[m] * 4);
        }

    const float bp0 = bproj[0], bp1 = bproj[1];
    int lenb = 0;
    if (w < 2 && l < 16) lenb = lengths[b0 + w * 16 + l];

    const int baseL0 = 160 + dirw * 160;
    const int baseL1 = dirw ? 0 : 160;
    const int hw1    = dirw ? 0 : 480;

    __syncthreads();

    for (int t = 0; t < 128; ++t) {
        f32x4 acc[10][2];
        // ---- Phase A: L0 GEMM (K=160: h0_d + x + pad) ----
#pragma unroll
        for (int m = 0; m < 10; ++m)
#pragma unroll
            for (int nt = 0; nt < 2; ++nt) {
                f16x4v bz = bz0[m][nt];
                acc[m][nt] = (f32x4){(float)bz[0], (float)bz[1], (float)bz[2], (float)bz[3]};
            }
#pragma unroll
        for (int ks = 0; ks < 5; ++ks) {
            f16x8 bf[2];
#pragma unroll
            for (int nt = 0; nt < 2; ++nt) {
                int row = nt * 16 + l15;
                int byte = row * 1312 + (baseL0 + ks * 32 + lg * 8) * 2;  byte ^= (row & 7) << 4;
                bf[nt] = *(const f16x8*)((const char*)tile + byte);
            }
#pragma unroll
            for (int m = 0; m < 10; ++m) {
                f16x8 a = *(const f16x8*)(pw0 + (((size_t)(w * 10 + m) * 5 + ks) * 64 + l) * 8);
                acc[m][0] = __builtin_amdgcn_mfma_f32_16x16x32_f16(a, bf[0], acc[m][0], 0, 0, 0);
                acc[m][1] = __builtin_amdgcn_mfma_f32_16x16x32_f16(a, bf[1], acc[m][1], 0, 0, 0);
            }
        }
        __syncthreads();
        // ---- Phase B: act0 -> h0 into tile ----
#pragma unroll
        for (int m = 0; m < 10; ++m)
#pragma unroll
            for (int nt = 0; nt < 2; ++nt) {
                float gi = sigm_(acc[m][nt][0]);
                float gf = sigm_(acc[m][nt][1]);
                float gg = tanh_(acc[m][nt][2]);
                float go = sigm_(acc[m][nt][3]);
                float c = gf * c0s[m][nt] + gi * gg;
                c0s[m][nt] = c;
                float h = go * tanh_(c);
                if (jj[m] < 150) {
                    int row = nt * 16 + l15;
                    int byte = row * 1312 + (baseL0 + jj[m]) * 2;  byte ^= (row & 7) << 4;
                    *(f16*)((char*)tile + byte) = (f16)h;
                }
            }
        __syncthreads();
        // ---- Phase C: L1 GEMM (K=480) ----
#pragma unroll
        for (int m = 0; m < 10; ++m) {
            f32x4 bi = (f32x4){(float)b1v[m][0], (float)b1v[m][1], (float)b1v[m][2], (float)b1v[m][3]};
            acc[m][0] = bi;  acc[m][1] = bi;
        }
#pragma unroll
        for (int ks = 0; ks < 15; ++ks) {
            f16x8 bf[2];
#pragma unroll
            for (int nt = 0; nt < 2; ++nt) {
                int row = nt * 16 + l15;
                int byte = row * 1312 + (baseL1 + ks * 32 + lg * 8) * 2;  byte ^= (row & 7) << 4;
                bf[nt] = *(const f16x8*)((const char*)tile + byte);
            }
#pragma unroll
            for (int m = 0; m < 10; ++m) {
                f16x8 a = *(const f16x8*)(pw1 + (((size_t)(w * 10 + m) * 15 + ks) * 64 + l) * 8);
                acc[m][0] = __builtin_amdgcn_mfma_f32_16x16x32_f16(a, bf[0], acc[m][0], 0, 0, 0);
                acc[m][1] = __builtin_amdgcn_mfma_f32_16x16x32_f16(a, bf[1], acc[m][1], 0, 0, 0);
            }
        }
        __syncthreads();
        // ---- Phase D: act1 -> h1 into tile ----
#pragma unroll
        for (int m = 0; m < 10; ++m)
#pragma unroll
            for (int nt = 0; nt < 2; ++nt) {
                float gi = sigm_(acc[m][nt][0]);
                float gf = sigm_(acc[m][nt][1]);
                float gg = tanh_(acc[m][nt][2]);
                float go = sigm_(acc[m][nt][3]);
                float c = gf * c1s[m][nt] + gi * gg;
                c1s[m][nt] = c;
                float h = go * tanh_(c);
                if (jj[m] < 150) {
                    int row = nt * 16 + l15;
                    int byte = row * 1312 + (hw1 + jj[m]) * 2;  byte ^= (row & 7) << 4;
                    *(f16*)((char*)tile + byte) = (f16)h;
                }
            }
        __syncthreads();
        // ---- Phase E: proj + output + x writeback (waves 0,1) ----
        if (w < 2) {
            f32x4 ap = (f32x4){0.f, 0.f, 0.f, 0.f};
#pragma unroll
            for (int ks = 0; ks < 20; ++ks) {
                int row = w * 16 + l15;
                int byte = row * 1312 + (ks * 32 + lg * 8) * 2;  byte ^= (row & 7) << 4;
                f16x8 bfp = *(const f16x8*)((const char*)tile + byte);
                f16x8 a = *(const f16x8*)(pwpj + ((size_t)ks * 64 + l) * 8);
                ap = __builtin_amdgcn_mfma_f32_16x16x32_f16(a, bfp, ap, 0, 0, 0);
            }
            if (l < 16) {
                float o0 = ap[0] + bp0, o1 = ap[1] + bp1;
                int b = b0 + w * 16 + l;
                bool live = (t < lenb);
                *(float2*)(out + ((size_t)b * 128 + t) * 2) =
                    make_float2(live ? o0 : 0.f, live ? o1 : 0.f);
                int row = w * 16 + l;
                f16x2v xv = {(f16)o0, (f16)o1};
                int byte1 = row * 1312 + 620;  byte1 ^= (row & 7) << 4;   // h0f x cols
                *(f16x2v*)((char*)tile + byte1) = xv;
                int byte2 = row * 1312 + 940;  byte2 ^= (row & 7) << 4;   // h0b x cols
                *(f16x2v*)((char*)tile + byte2) = xv;
            }
        }
        __syncthreads();
    }
}

extern "C" void kernel_launch(void* const* d_in, const int* in_sizes, int n_in,
                              void* d_out, int out_size, void* d_ws, size_t ws_size,
                              hipStream_t stream) {
    const float* noise = (const float*)d_in[0];
    const float* targ  = (const float*)d_in[1];
    const float* msk   = (const float*)d_in[2];
    const int*   lens  = (const int*)d_in[3];
    const float* Wih0  = (const float*)d_in[5];
    const float* Whh0  = (const float*)d_in[6];
    const float* bl0   = (const float*)d_in[7];
    const float* Wih1  = (const float*)d_in[8];
    const float* Whh1  = (const float*)d_in[9];
    const float* bl1   = (const float*)d_in[10];
    const float* Wp    = (const float*)d_in[11];
    const float* bpj   = (const float*)d_in[12];
    const float* Wit   = (const float*)d_in[13];
    const float* bit   = (const float*)d_in[14];
    const float* Wtk   = (const float*)d_in[15];
    const float* btk   = (const float*)d_in[16];

    char* ws = (char*)d_ws;
    f16*   HINIT = (f16*)(ws);
    float* CINIT = (float*)(ws + OFF_CINIT);
    f16*   BIAS0 = (f16*)(ws + OFF_BIAS0);
    f16*   PW0   = (f16*)(ws + OFF_PW0);
    f16*   PW1   = (f16*)(ws + OFF_PW1);
    f16*   PWPJ  = (f16*)(ws + OFF_PWPJ);
    f16*   B1P   = (f16*)(ws + OFF_B1P);

    hipLaunchKernelGGL(k_init,  dim3(10240), dim3(256), 0, stream,
                       noise, targ, msk, Wit, bit, Wtk, btk, HINIT, CINIT);
    hipLaunchKernelGGL(k_pack,  dim3(3245), dim3(256), 0, stream,
                       Wih0, Whh0, Wih1, Whh1, Wp, bl1, PW0, PW1, PWPJ, B1P);
    hipLaunchKernelGGL(k_bias0, dim3(10240), dim3(256), 0, stream,
                       Wih0, bl0, targ, msk, BIAS0);
    hipLaunchKernelGGL(lstm_main, dim3(64), dim3(512), 0, stream,
                       HINIT, CINIT, BIAS0, PW0, PW1, PWPJ, B1P, bpj, lens,
                       (float*)d_out);
}

// Round 4
// 8009.898 us; speedup vs baseline: 1.2841x; 1.2543x over previous
//
#include <hip/hip_runtime.h>

// ---------------------------------------------------------------------------
// 2-layer "bidirectional" LSTM generator, B=2048, T=128, HID=150.
// R3 redesign: 64 WGs x 1024 threads (16 waves, 4/SIMD). Each wave owns
// 5 M-tiles (gates packed 4j+{i,f,g,o}) x BOTH batch N-tiles -> acc[5][2].
// Designed to fit the 128-VGPR cap the allocator insists on (R0-R2 spilled
// ~150MB scratch -> L2 thrash -> serialized HBM-latency weight loads).
// bias0/b_l1/proj weights live in LDS (staged once); A-frags stream from L2
// with a register double-buffer (unrolled, static indexing).
// ---------------------------------------------------------------------------

typedef _Float16 f16;
typedef _Float16 f16x8 __attribute__((ext_vector_type(8)));
typedef _Float16 f16x4v __attribute__((ext_vector_type(4)));
typedef _Float16 f16x2v __attribute__((ext_vector_type(2)));
typedef float    f32x4 __attribute__((ext_vector_type(4)));

#define LOG2E 1.44269504f

__device__ __forceinline__ float sigm_(float x) {
    float e = __builtin_amdgcn_exp2f(-LOG2E * x);
    return __builtin_amdgcn_rcpf(1.f + e);
}
__device__ __forceinline__ float tanh_(float x) {
    float e = __builtin_amdgcn_exp2f(2.f * LOG2E * x);
    return 1.f - 2.f * __builtin_amdgcn_rcpf(1.f + e);
}

// ---------------- ws layout (bytes) ----------------
#define OFF_CINIT 2621440
#define OFF_BIAS0 7864320
#define OFF_PW0   13107200
#define OFF_PW1   13516800
#define OFF_PWPJ  14745600
#define OFF_B1P   14766080

// z[b] = [noise(100), targets(2), masks(3)]
__device__ float dot105(const float* __restrict__ noise,
                        const float* __restrict__ targ,
                        const float* __restrict__ msk,
                        const float* __restrict__ Wrow, int bb) {
    float s = 0.f;
    const float* nz = noise + (size_t)bb * 100;
#pragma unroll 4
    for (int k = 0; k < 100; ++k) s += nz[k] * Wrow[k];
    s += targ[bb*2+0]*Wrow[100] + targ[bb*2+1]*Wrow[101];
    s += msk[bb*3+0]*Wrow[102] + msk[bb*3+1]*Wrow[103] + msk[bb*3+2]*Wrow[104];
    return s;
}

// Build HINIT (tile layout [h1b | h0f,x | h0b,x | h1f], regions of 160) and CINIT.
// Replicates torch's (B,1200).view(8,B,150) on the row-major init-matmul buffer.
__global__ void k_init(const float* __restrict__ noise, const float* __restrict__ targ,
                       const float* __restrict__ msk,
                       const float* __restrict__ Wih, const float* __restrict__ bih,
                       const float* __restrict__ Wtk, const float* __restrict__ btk,
                       f16* __restrict__ hinit, float* __restrict__ cinitp) {
    int gid = blockIdx.x * 256 + threadIdx.x;   // 2048*1280 exact
    int b = gid / 1280, c = gid % 1280;
    if (c < 640) {
        int reg = c / 160, loc = c % 160;
        float v = 0.f; bool has = false;
        if (loc < 150) {
            int q = (reg == 0) ? 3 : (reg == 1) ? 0 : (reg == 2) ? 1 : 2; // h1b,h0f,h0b,h1f
            size_t i = (size_t)q * 2048 * 150 + (size_t)b * 150 + loc;
            int bb = (int)(i / 1200), rr = (int)(i % 1200);
            v = dot105(noise, targ, msk, Wih + (size_t)rr * 105, bb) + bih[rr];
            has = true;
        } else if (loc < 152 && (reg == 1 || reg == 2)) {
            int o = loc - 150;
            v = dot105(noise, targ, msk, Wtk + o * 105, b) + btk[o];
            has = true;
        }
        hinit[(size_t)b * 640 + c] = has ? (f16)v : (f16)0.f;
    } else {
        int idx = c - 640;                       // layer*320 + d*160 + j
        int layer = idx / 320, r = idx % 320, d = r / 160, j = r % 160;
        float v = 0.f;
        if (j < 150) {
            int q = 4 + layer * 2 + d;
            size_t i = (size_t)q * 2048 * 150 + (size_t)b * 150 + j;
            int bb = (int)(i / 1200), rr = (int)(i % 1200);
            v = dot105(noise, targ, msk, Wih + (size_t)rr * 105, bb) + bih[rr];
        }
        cinitp[(((size_t)layer * 2048 + b) * 2 + d) * 160 + j] = v;
    }
}

// Pack weights into MFMA A-fragment order. A-frag lane l holds
// A[row=l&15][k=(l>>4)*8+e]. M-row r16 -> j=jt*4+(r16>>2), gate g=r16&3.
__global__ void k_pack(const float* __restrict__ Wih0, const float* __restrict__ Whh0,
                       const float* __restrict__ Wih1, const float* __restrict__ Whh1,
                       const float* __restrict__ Wp,   const float* __restrict__ bl1,
                       f16* __restrict__ pw0, f16* __restrict__ pw1,
                       f16* __restrict__ pwpj, f16* __restrict__ b1p) {
    int gid = blockIdx.x * 256 + threadIdx.x;
    const int N0 = 80*5*512, N1 = 80*15*512, NP = 20*512;
    if (gid < N0) {
        int e = gid & 7, l = (gid >> 3) & 63, f = gid >> 9;
        int ks = f % 5, mt = f / 5;
        int d = mt / 40, jt = mt % 40, r16 = l & 15;
        int j = jt * 4 + (r16 >> 2), g = r16 & 3;
        int k = ks * 32 + (l >> 4) * 8 + e;
        float v = 0.f;
        if (j < 150) {
            int R = d * 600 + g * 150 + j;
            if (k < 150)      v = Whh0[(size_t)R * 150 + k];
            else if (k < 152) v = Wih0[(size_t)R * 7 + (k - 150)];
        }
        pw0[gid] = (f16)v;  return;
    }
    gid -= N0;
    if (gid < N1) {
        int e = gid & 7, l = (gid >> 3) & 63, f = gid >> 9;
        int ks = f % 15, mt = f / 15;
        int d = mt / 40, jt = mt % 40, r16 = l & 15;
        int j = jt * 4 + (r16 >> 2), g = r16 & 3;
        int k = ks * 32 + (l >> 4) * 8 + e;
        float v = 0.f;
        if (j < 150) {
            int R = d * 600 + g * 150 + j;
            if (d == 0) { // window [h0f,pad | h0b,pad | h1f,pad]
                if (k < 150)                 v = Wih1[(size_t)R * 300 + k];
                else if (k >= 160 && k < 310) v = Wih1[(size_t)R * 300 + (k - 10)];
                else if (k >= 320 && k < 470) v = Whh1[(size_t)R * 150 + (k - 320)];
            } else {      // window [h1b,pad | h0f,pad | h0b,pad]
                if (k < 150)                 v = Whh1[(size_t)R * 150 + k];
                else if (k >= 160 && k < 310) v = Wih1[(size_t)R * 300 + (k - 160)];
                else if (k >= 320 && k < 470) v = Wih1[(size_t)R * 300 + (k - 170)];
            }
        }
        pw1[gid] = (f16)v;  return;
    }
    gid -= N1;
    if (gid < NP) {
        int e = gid & 7, l = (gid >> 3) & 63, ks = gid >> 9;
        int r16 = l & 15;
        int k = ks * 32 + (l >> 4) * 8 + e;
        float v = 0.f;
        if (r16 < 2) {  // whole-tile window: h1b at cols 0..149, h1f at 480..629
            if (k < 150)                  v = Wp[r16 * 300 + 150 + k];
            else if (k >= 480 && k < 630) v = Wp[r16 * 300 + (k - 480)];
        }
        pwpj[gid] = (f16)v;  return;
    }
    gid -= NP;
    {   // b_l1 gate-packed: [mt][r16]
        int r16 = gid & 15, mt = gid >> 4;
        int d = mt / 40, jt = mt % 40;
        int j = jt * 4 + (r16 >> 2), g = r16 & 3;
        float v = (j < 150) ? bl1[d * 600 + g * 150 + j] : 0.f;
        b1p[gid] = (f16)v;
    }
}

// bias0[b][d][j][g] = b_l0 + Wih_l0[:,:,2:7] @ y[b]   (time-invariant L0 input part)
__global__ void k_bias0(const float* __restrict__ Wih0, const float* __restrict__ bl0,
                        const float* __restrict__ targ, const float* __restrict__ msk,
                        f16* __restrict__ bias0) {
    int gid = blockIdx.x * 256 + threadIdx.x;  // 2048*1280 exact
    int b = gid / 1280, r = gid % 1280;
    int d = r / 640, s = r % 640, j = s >> 2, g = s & 3;
    float v = 0.f;
    if (j < 150) {
        int R = d * 600 + g * 150 + j;
        const float* wr = Wih0 + (size_t)R * 7;
        v = bl0[R] + wr[2]*targ[b*2+0] + wr[3]*targ[b*2+1]
                   + wr[4]*msk[b*3+0] + wr[5]*msk[b*3+1] + wr[6]*msk[b*3+2];
    }
    bias0[gid] = (f16)v;
}

// ---------------------------------------------------------------------------
// Main persistent kernel: 64 WGs x 1024 thr (16 waves), 32 batch rows per WG.
// Wave w owns M-tiles [w*5, w*5+5) (w<8: fwd dir; w>=8: bwd) x both N-tiles.
// Tile cols: [0:h1b | 160:h0f(+x@150,151) | 320:h0b(+x) | 480:h1f], stride 656
// f16 (1312B), rows XOR-swizzled by (row&7)<<4.
// LDS (f16 idx): tile @0 (20992), bias0L @20992 (40960, swizzled, stride 1280),
// b1pl @61952 (1280), pjl @63232 (10240). Total 146944 B -> 1 WG/CU.
// ---------------------------------------------------------------------------
__global__ __launch_bounds__(1024)
__attribute__((amdgpu_waves_per_eu(4, 4)))
void lstm_main(
    const f16* __restrict__ hinit, const float* __restrict__ cinit,
    const f16* __restrict__ bias0, const f16* __restrict__ pw0,
    const f16* __restrict__ pw1,   const f16* __restrict__ pwpj,
    const f16* __restrict__ b1p,   const float* __restrict__ bproj,
    const int* __restrict__ lengths, float* __restrict__ out) {
    __shared__ f16 lds[73472];
    char* ldsb = (char*)lds;
    const int tid = threadIdx.x;
    const int w = tid >> 6, l = tid & 63;
    const int b0 = blockIdx.x * 32;
    const int l15 = l & 15, lg = l >> 4;
    const int dirw = w >> 3;
    const int mtb = w * 5;

    // ---- stage LDS ----
    for (int it = tid; it < 32 * 80; it += 1024) {        // tile <- HINIT
        int row = it / 80, c8 = (it % 80) * 8;
        f16x8 v = *(const f16x8*)(hinit + (size_t)(b0 + row) * 640 + c8);
        int byte = row * 1312 + c8 * 2;  byte ^= (row & 7) << 4;
        *(f16x8*)(ldsb + byte) = v;
    }
    for (int it = tid; it < 32 * 160; it += 1024) {       // bias0L
        int row = it / 160, c8 = (it % 160) * 8;
        f16x8 v = *(const f16x8*)(bias0 + (size_t)(b0 + row) * 1280 + c8);
        int byte = 41984 + row * 2560 + c8 * 2;  byte ^= (row & 7) << 4;
        *(f16x8*)(ldsb + byte) = v;
    }
    for (int it = tid; it < 160; it += 1024)              // b1pl
        *(f16x8*)(lds + 61952 + it * 8) = *(const f16x8*)(b1p + it * 8);
    for (int it = tid; it < 1280; it += 1024)             // pjl
        *(f16x8*)(lds + 63232 + it * 8) = *(const f16x8*)(pwpj + it * 8);

    int jj[5];
#pragma unroll
    for (int m = 0; m < 5; ++m) jj[m] = ((mtb + m) % 40) * 4 + lg;

    float c0s[5][2], c1s[5][2];
#pragma unroll
    for (int m = 0; m < 5; ++m)
#pragma unroll
        for (int nt = 0; nt < 2; ++nt) {
            int b = b0 + nt * 16 + l15;
            c0s[m][nt] = cinit[((size_t)b * 2 + dirw) * 160 + jj[m]];
            c1s[m][nt] = cinit[(((size_t)2048 + b) * 2 + dirw) * 160 + jj[m]];
        }

    const float bp0 = bproj[0], bp1 = bproj[1];
    int lenb = 0;
    if (w < 2 && l < 16) lenb = lengths[b0 + w * 16 + l];

    const int baseL0 = 160 + dirw * 160;
    const int baseL1 = dirw ? 0 : 160;
    const int hw1    = dirw ? 0 : 480;
    const f16* pwa = pw0 + (size_t)mtb * 5 * 512 + l * 8;
    const f16* pwc = pw1 + (size_t)mtb * 15 * 512 + l * 8;

    __syncthreads();

    for (int t = 0; t < 128; ++t) {
        f32x4 acc[5][2];
        // ---- Phase A: L0 GEMM (K=160) ----
#pragma unroll
        for (int m = 0; m < 5; ++m)
#pragma unroll
            for (int nt = 0; nt < 2; ++nt) {
                int row = nt * 16 + l15;
                int byte = 41984 + row * 2560 + (dirw * 640 + jj[m] * 4) * 2;
                byte ^= (row & 7) << 4;
                f16x4v bz = *(const f16x4v*)(ldsb + byte);
                acc[m][nt] = (f32x4){(float)bz[0], (float)bz[1], (float)bz[2], (float)bz[3]};
            }
        {
            f16x8 af[5];
#pragma unroll
            for (int m = 0; m < 5; ++m) af[m] = *(const f16x8*)(pwa + m * 5 * 512);
#pragma unroll
            for (int ks = 0; ks < 5; ++ks) {
                f16x8 nf[5];
                if (ks < 4) {
#pragma unroll
                    for (int m = 0; m < 5; ++m)
                        nf[m] = *(const f16x8*)(pwa + (m * 5 + ks + 1) * 512);
                }
                f16x8 bfr[2];
#pragma unroll
                for (int nt = 0; nt < 2; ++nt) {
                    int row = nt * 16 + l15;
                    int byte = row * 1312 + (baseL0 + ks * 32 + lg * 8) * 2;
                    byte ^= (row & 7) << 4;
                    bfr[nt] = *(const f16x8*)(ldsb + byte);
                }
#pragma unroll
                for (int m = 0; m < 5; ++m) {
                    acc[m][0] = __builtin_amdgcn_mfma_f32_16x16x32_f16(af[m], bfr[0], acc[m][0], 0, 0, 0);
                    acc[m][1] = __builtin_amdgcn_mfma_f32_16x16x32_f16(af[m], bfr[1], acc[m][1], 0, 0, 0);
                }
                if (ks < 4) {
#pragma unroll
                    for (int m = 0; m < 5; ++m) af[m] = nf[m];
                }
            }
        }
        __syncthreads();
        // ---- Phase B: act0 -> h0 into tile ----
#pragma unroll
        for (int m = 0; m < 5; ++m)
#pragma unroll
            for (int nt = 0; nt < 2; ++nt) {
                float gi = sigm_(acc[m][nt][0]);
                float gf = sigm_(acc[m][nt][1]);
                float gg = tanh_(acc[m][nt][2]);
                float go = sigm_(acc[m][nt][3]);
                float c = gf * c0s[m][nt] + gi * gg;
                c0s[m][nt] = c;
                float h = go * tanh_(c);
                if (jj[m] < 150) {
                    int row = nt * 16 + l15;
                    int byte = row * 1312 + (baseL0 + jj[m]) * 2;  byte ^= (row & 7) << 4;
                    *(f16*)(ldsb + byte) = (f16)h;
                }
            }
        __syncthreads();
        // ---- Phase C: L1 GEMM (K=480) ----
#pragma unroll
        for (int m = 0; m < 5; ++m) {
            f16x4v b1 = *(const f16x4v*)(lds + 61952 + (mtb + m) * 16 + lg * 4);
            f32x4 bi = (f32x4){(float)b1[0], (float)b1[1], (float)b1[2], (float)b1[3]};
            acc[m][0] = bi;  acc[m][1] = bi;
        }
        {
            f16x8 af[5];
#pragma unroll
            for (int m = 0; m < 5; ++m) af[m] = *(const f16x8*)(pwc + m * 15 * 512);
#pragma unroll
            for (int ks = 0; ks < 15; ++ks) {
                f16x8 nf[5];
                if (ks < 14) {
#pragma unroll
                    for (int m = 0; m < 5; ++m)
                        nf[m] = *(const f16x8*)(pwc + (m * 15 + ks + 1) * 512);
                }
                f16x8 bfr[2];
#pragma unroll
                for (int nt = 0; nt < 2; ++nt) {
                    int row = nt * 16 + l15;
                    int byte = row * 1312 + (baseL1 + ks * 32 + lg * 8) * 2;
                    byte ^= (row & 7) << 4;
                    bfr[nt] = *(const f16x8*)(ldsb + byte);
                }
#pragma unroll
                for (int m = 0; m < 5; ++m) {
                    acc[m][0] = __builtin_amdgcn_mfma_f32_16x16x32_f16(af[m], bfr[0], acc[m][0], 0, 0, 0);
                    acc[m][1] = __builtin_amdgcn_mfma_f32_16x16x32_f16(af[m], bfr[1], acc[m][1], 0, 0, 0);
                }
                if (ks < 14) {
#pragma unroll
                    for (int m = 0; m < 5; ++m) af[m] = nf[m];
                }
            }
        }
        __syncthreads();
        // ---- Phase D: act1 -> h1 into tile ----
#pragma unroll
        for (int m = 0; m < 5; ++m)
#pragma unroll
            for (int nt = 0; nt < 2; ++nt) {
                float gi = sigm_(acc[m][nt][0]);
                float gf = sigm_(acc[m][nt][1]);
                float gg = tanh_(acc[m][nt][2]);
                float go = sigm_(acc[m][nt][3]);
                float c = gf * c1s[m][nt] + gi * gg;
                c1s[m][nt] = c;
                float h = go * tanh_(c);
                if (jj[m] < 150) {
                    int row = nt * 16 + l15;
                    int byte = row * 1312 + (hw1 + jj[m]) * 2;  byte ^= (row & 7) << 4;
                    *(f16*)(ldsb + byte) = (f16)h;
                }
            }
        __syncthreads();
        // ---- Phase E: proj + output + x writeback (waves 0,1) ----
        if (w < 2) {
            f32x4 ap = (f32x4){0.f, 0.f, 0.f, 0.f};
#pragma unroll
            for (int ks = 0; ks < 20; ++ks) {
                int row = w * 16 + l15;
                int byte = row * 1312 + (ks * 32 + lg * 8) * 2;  byte ^= (row & 7) << 4;
                f16x8 bfp = *(const f16x8*)(ldsb + byte);
                f16x8 a = *(const f16x8*)(lds + 63232 + ks * 512 + l * 8);
                ap = __builtin_amdgcn_mfma_f32_16x16x32_f16(a, bfp, ap, 0, 0, 0);
            }
            if (l < 16) {
                float o0 = ap[0] + bp0, o1 = ap[1] + bp1;
                int b = b0 + w * 16 + l;
                bool live = (t < lenb);
                *(float2*)(out + ((size_t)b * 128 + t) * 2) =
                    make_float2(live ? o0 : 0.f, live ? o1 : 0.f);
                int row = w * 16 + l;
                f16x2v xv = {(f16)o0, (f16)o1};
                int byte1 = row * 1312 + 620;  byte1 ^= (row & 7) << 4;   // h0f x cols
                *(f16x2v*)(ldsb + byte1) = xv;
                int byte2 = row * 1312 + 940;  byte2 ^= (row & 7) << 4;   // h0b x cols
                *(f16x2v*)(ldsb + byte2) = xv;
            }
        }
        __syncthreads();
    }
}

extern "C" void kernel_launch(void* const* d_in, const int* in_sizes, int n_in,
                              void* d_out, int out_size, void* d_ws, size_t ws_size,
                              hipStream_t stream) {
    const float* noise = (const float*)d_in[0];
    const float* targ  = (const float*)d_in[1];
    const float* msk   = (const float*)d_in[2];
    const int*   lens  = (const int*)d_in[3];
    const float* Wih0  = (const float*)d_in[5];
    const float* Whh0  = (const float*)d_in[6];
    const float* bl0   = (const float*)d_in[7];
    const float* Wih1  = (const float*)d_in[8];
    const float* Whh1  = (const float*)d_in[9];
    const float* bl1   = (const float*)d_in[10];
    const float* Wp    = (const float*)d_in[11];
    const float* bpj   = (const float*)d_in[12];
    const float* Wit   = (const float*)d_in[13];
    const float* bit   = (const float*)d_in[14];
    const float* Wtk   = (const float*)d_in[15];
    const float* btk   = (const float*)d_in[16];

    char* ws = (char*)d_ws;
    f16*   HINIT = (f16*)(ws);
    float* CINIT = (float*)(ws + OFF_CINIT);
    f16*   BIAS0 = (f16*)(ws + OFF_BIAS0);
    f16*   PW0   = (f16*)(ws + OFF_PW0);
    f16*   PW1   = (f16*)(ws + OFF_PW1);
    f16*   PWPJ  = (f16*)(ws + OFF_PWPJ);
    f16*   B1P   = (f16*)(ws + OFF_B1P);

    hipLaunchKernelGGL(k_init,  dim3(10240), dim3(256), 0, stream,
                       noise, targ, msk, Wit, bit, Wtk, btk, HINIT, CINIT);
    hipLaunchKernelGGL(k_pack,  dim3(3245), dim3(256), 0, stream,
                       Wih0, Whh0, Wih1, Whh1, Wp, bl1, PW0, PW1, PWPJ, B1P);
    hipLaunchKernelGGL(k_bias0, dim3(10240), dim3(256), 0, stream,
                       Wih0, bl0, targ, msk, BIAS0);
    hipLaunchKernelGGL(lstm_main, dim3(64), dim3(1024), 0, stream,
                       HINIT, CINIT, BIAS0, PW0, PW1, PWPJ, B1P, bpj, lens,
                       (float*)d_out);
}

// Round 5
// 8002.381 us; speedup vs baseline: 1.2853x; 1.0009x over previous
//
#include <hip/hip_runtime.h>

// ---------------------------------------------------------------------------
// 2-layer "bidirectional" LSTM generator, B=2048, T=128, HID=150.
// 64 WGs x 1024 threads (16 waves, 4/SIMD, 1 WG/CU by LDS). Each wave owns
// 5 M-tiles (gates packed 4j+{i,f,g,o}) x both batch N-tiles -> acc[5][2].
// bias0/b_l1/proj weights in LDS (staged once); A-frags stream from L2.
// R5: removed the af/nf register double-buffer (40 VGPRs) that overflowed
// the 64-reg arch half of the 128-total budget (R4: 124 MB spill writes ->
// L2 thrash -> 7.3 GB HBM weight re-fetch). Simple per-m A-frag loads; rely
// on unroll + 4-wave TLP for latency hiding.
// ---------------------------------------------------------------------------

typedef _Float16 f16;
typedef _Float16 f16x8 __attribute__((ext_vector_type(8)));
typedef _Float16 f16x4v __attribute__((ext_vector_type(4)));
typedef _Float16 f16x2v __attribute__((ext_vector_type(2)));
typedef float    f32x4 __attribute__((ext_vector_type(4)));

#define LOG2E 1.44269504f

__device__ __forceinline__ float sigm_(float x) {
    float e = __builtin_amdgcn_exp2f(-LOG2E * x);
    return __builtin_amdgcn_rcpf(1.f + e);
}
__device__ __forceinline__ float tanh_(float x) {
    float e = __builtin_amdgcn_exp2f(2.f * LOG2E * x);
    return 1.f - 2.f * __builtin_amdgcn_rcpf(1.f + e);
}

// ---------------- ws layout (bytes) ----------------
#define OFF_CINIT 2621440
#define OFF_BIAS0 7864320
#define OFF_PW0   13107200
#define OFF_PW1   13516800
#define OFF_PWPJ  14745600
#define OFF_B1P   14766080

// z[b] = [noise(100), targets(2), masks(3)]
__device__ float dot105(const float* __restrict__ noise,
                        const float* __restrict__ targ,
                        const float* __restrict__ msk,
                        const float* __restrict__ Wrow, int bb) {
    float s = 0.f;
    const float* nz = noise + (size_t)bb * 100;
#pragma unroll 4
    for (int k = 0; k < 100; ++k) s += nz[k] * Wrow[k];
    s += targ[bb*2+0]*Wrow[100] + targ[bb*2+1]*Wrow[101];
    s += msk[bb*3+0]*Wrow[102] + msk[bb*3+1]*Wrow[103] + msk[bb*3+2]*Wrow[104];
    return s;
}

// Build HINIT (tile layout [h1b | h0f,x | h0b,x | h1f], regions of 160) and CINIT.
// Replicates torch's (B,1200).view(8,B,150) on the row-major init-matmul buffer.
__global__ void k_init(const float* __restrict__ noise, const float* __restrict__ targ,
                       const float* __restrict__ msk,
                       const float* __restrict__ Wih, const float* __restrict__ bih,
                       const float* __restrict__ Wtk, const float* __restrict__ btk,
                       f16* __restrict__ hinit, float* __restrict__ cinitp) {
    int gid = blockIdx.x * 256 + threadIdx.x;   // 2048*1280 exact
    int b = gid / 1280, c = gid % 1280;
    if (c < 640) {
        int reg = c / 160, loc = c % 160;
        float v = 0.f; bool has = false;
        if (loc < 150) {
            int q = (reg == 0) ? 3 : (reg == 1) ? 0 : (reg == 2) ? 1 : 2; // h1b,h0f,h0b,h1f
            size_t i = (size_t)q * 2048 * 150 + (size_t)b * 150 + loc;
            int bb = (int)(i / 1200), rr = (int)(i % 1200);
            v = dot105(noise, targ, msk, Wih + (size_t)rr * 105, bb) + bih[rr];
            has = true;
        } else if (loc < 152 && (reg == 1 || reg == 2)) {
            int o = loc - 150;
            v = dot105(noise, targ, msk, Wtk + o * 105, b) + btk[o];
            has = true;
        }
        hinit[(size_t)b * 640 + c] = has ? (f16)v : (f16)0.f;
    } else {
        int idx = c - 640;                       // layer*320 + d*160 + j
        int layer = idx / 320, r = idx % 320, d = r / 160, j = r % 160;
        float v = 0.f;
        if (j < 150) {
            int q = 4 + layer * 2 + d;
            size_t i = (size_t)q * 2048 * 150 + (size_t)b * 150 + j;
            int bb = (int)(i / 1200), rr = (int)(i % 1200);
            v = dot105(noise, targ, msk, Wih + (size_t)rr * 105, bb) + bih[rr];
        }
        cinitp[(((size_t)layer * 2048 + b) * 2 + d) * 160 + j] = v;
    }
}

// Pack weights into MFMA A-fragment order. A-frag lane l holds
// A[row=l&15][k=(l>>4)*8+e]. M-row r16 -> j=jt*4+(r16>>2), gate g=r16&3.
__global__ void k_pack(const float* __restrict__ Wih0, const float* __restrict__ Whh0,
                       const float* __restrict__ Wih1, const float* __restrict__ Whh1,
                       const float* __restrict__ Wp,   const float* __restrict__ bl1,
                       f16* __restrict__ pw0, f16* __restrict__ pw1,
                       f16* __restrict__ pwpj, f16* __restrict__ b1p) {
    int gid = blockIdx.x * 256 + threadIdx.x;
    const int N0 = 80*5*512, N1 = 80*15*512, NP = 20*512;
    if (gid < N0) {
        int e = gid & 7, l = (gid >> 3) & 63, f = gid >> 9;
        int ks = f % 5, mt = f / 5;
        int d = mt / 40, jt = mt % 40, r16 = l & 15;
        int j = jt * 4 + (r16 >> 2), g = r16 & 3;
        int k = ks * 32 + (l >> 4) * 8 + e;
        float v = 0.f;
        if (j < 150) {
            int R = d * 600 + g * 150 + j;
            if (k < 150)      v = Whh0[(size_t)R * 150 + k];
            else if (k < 152) v = Wih0[(size_t)R * 7 + (k - 150)];
        }
        pw0[gid] = (f16)v;  return;
    }
    gid -= N0;
    if (gid < N1) {
        int e = gid & 7, l = (gid >> 3) & 63, f = gid >> 9;
        int ks = f % 15, mt = f / 15;
        int d = mt / 40, jt = mt % 40, r16 = l & 15;
        int j = jt * 4 + (r16 >> 2), g = r16 & 3;
        int k = ks * 32 + (l >> 4) * 8 + e;
        float v = 0.f;
        if (j < 150) {
            int R = d * 600 + g * 150 + j;
            if (d == 0) { // window [h0f,pad | h0b,pad | h1f,pad]
                if (k < 150)                 v = Wih1[(size_t)R * 300 + k];
                else if (k >= 160 && k < 310) v = Wih1[(size_t)R * 300 + (k - 10)];
                else if (k >= 320 && k < 470) v = Whh1[(size_t)R * 150 + (k - 320)];
            } else {      // window [h1b,pad | h0f,pad | h0b,pad]
                if (k < 150)                 v = Whh1[(size_t)R * 150 + k];
                else if (k >= 160 && k < 310) v = Wih1[(size_t)R * 300 + (k - 160)];
                else if (k >= 320 && k < 470) v = Wih1[(size_t)R * 300 + (k - 170)];
            }
        }
        pw1[gid] = (f16)v;  return;
    }
    gid -= N1;
    if (gid < NP) {
        int e = gid & 7, l = (gid >> 3) & 63, ks = gid >> 9;
        int r16 = l & 15;
        int k = ks * 32 + (l >> 4) * 8 + e;
        float v = 0.f;
        if (r16 < 2) {  // whole-tile window: h1b at cols 0..149, h1f at 480..629
            if (k < 150)                  v = Wp[r16 * 300 + 150 + k];
            else if (k >= 480 && k < 630) v = Wp[r16 * 300 + (k - 480)];
        }
        pwpj[gid] = (f16)v;  return;
    }
    gid -= NP;
    {   // b_l1 gate-packed: [mt][r16]
        int r16 = gid & 15, mt = gid >> 4;
        int d = mt / 40, jt = mt % 40;
        int j = jt * 4 + (r16 >> 2), g = r16 & 3;
        float v = (j < 150) ? bl1[d * 600 + g * 150 + j] : 0.f;
        b1p[gid] = (f16)v;
    }
}

// bias0[b][d][j][g] = b_l0 + Wih_l0[:,:,2:7] @ y[b]   (time-invariant L0 input part)
__global__ void k_bias0(const float* __restrict__ Wih0, const float* __restrict__ bl0,
                        const float* __restrict__ targ, const float* __restrict__ msk,
                        f16* __restrict__ bias0) {
    int gid = blockIdx.x * 256 + threadIdx.x;  // 2048*1280 exact
    int b = gid / 1280, r = gid % 1280;
    int d = r / 640, s = r % 640, j = s >> 2, g = s & 3;
    float v = 0.f;
    if (j < 150) {
        int R = d * 600 + g * 150 + j;
        const float* wr = Wih0 + (size_t)R * 7;
        v = bl0[R] + wr[2]*targ[b*2+0] + wr[3]*targ[b*2+1]
                   + wr[4]*msk[b*3+0] + wr[5]*msk[b*3+1] + wr[6]*msk[b*3+2];
    }
    bias0[gid] = (f16)v;
}

// ---------------------------------------------------------------------------
// Main persistent kernel: 64 WGs x 1024 thr (16 waves), 32 batch rows per WG.
// Wave w owns M-tiles [w*5, w*5+5) (w<8: fwd dir; w>=8: bwd) x both N-tiles.
// Tile cols: [0:h1b | 160:h0f(+x@150,151) | 320:h0b(+x) | 480:h1f], stride 656
// f16 (1312B), rows XOR-swizzled by (row&7)<<4.
// LDS (f16 idx): tile @0 (20992), bias0L @20992 (40960, swizzled, stride 1280),
// b1pl @61952 (1280), pjl @63232 (10240). Total 146944 B -> 1 WG/CU.
// ---------------------------------------------------------------------------
__global__ __launch_bounds__(1024)
__attribute__((amdgpu_waves_per_eu(4, 4)))
void lstm_main(
    const f16* __restrict__ hinit, const float* __restrict__ cinit,
    const f16* __restrict__ bias0, const f16* __restrict__ pw0,
    const f16* __restrict__ pw1,   const f16* __restrict__ pwpj,
    const f16* __restrict__ b1p,   const float* __restrict__ bproj,
    const int* __restrict__ lengths, float* __restrict__ out) {
    __shared__ f16 lds[73472];
    char* ldsb = (char*)lds;
    const int tid = threadIdx.x;
    const int w = tid >> 6, l = tid & 63;
    const int b0 = blockIdx.x * 32;
    const int l15 = l & 15, lg = l >> 4;
    const int dirw = w >> 3;
    const int mtb = w * 5;

    // ---- stage LDS ----
    for (int it = tid; it < 32 * 80; it += 1024) {        // tile <- HINIT
        int row = it / 80, c8 = (it % 80) * 8;
        f16x8 v = *(const f16x8*)(hinit + (size_t)(b0 + row) * 640 + c8);
        int byte = row * 1312 + c8 * 2;  byte ^= (row & 7) << 4;
        *(f16x8*)(ldsb + byte) = v;
    }
    for (int it = tid; it < 32 * 160; it += 1024) {       // bias0L
        int row = it / 160, c8 = (it % 160) * 8;
        f16x8 v = *(const f16x8*)(bias0 + (size_t)(b0 + row) * 1280 + c8);
        int byte = 41984 + row * 2560 + c8 * 2;  byte ^= (row & 7) << 4;
        *(f16x8*)(ldsb + byte) = v;
    }
    for (int it = tid; it < 160; it += 1024)              // b1pl
        *(f16x8*)(lds + 61952 + it * 8) = *(const f16x8*)(b1p + it * 8);
    for (int it = tid; it < 1280; it += 1024)             // pjl
        *(f16x8*)(lds + 63232 + it * 8) = *(const f16x8*)(pwpj + it * 8);

    int jj[5];
#pragma unroll
    for (int m = 0; m < 5; ++m) jj[m] = ((mtb + m) % 40) * 4 + lg;

    float c0s[5][2], c1s[5][2];
#pragma unroll
    for (int m = 0; m < 5; ++m)
#pragma unroll
        for (int nt = 0; nt < 2; ++nt) {
            int b = b0 + nt * 16 + l15;
            c0s[m][nt] = cinit[((size_t)b * 2 + dirw) * 160 + jj[m]];
            c1s[m][nt] = cinit[(((size_t)2048 + b) * 2 + dirw) * 160 + jj[m]];
        }

    const float bp0 = bproj[0], bp1 = bproj[1];
    int lenb = 0;
    if (w < 2 && l < 16) lenb = lengths[b0 + w * 16 + l];

    const int baseL0 = 160 + dirw * 160;
    const int baseL1 = dirw ? 0 : 160;
    const int hw1    = dirw ? 0 : 480;
    const f16* pwa = pw0 + (size_t)mtb * 5 * 512 + l * 8;
    const f16* pwc = pw1 + (size_t)mtb * 15 * 512 + l * 8;

    __syncthreads();

    for (int t = 0; t < 128; ++t) {
        f32x4 acc[5][2];
        // ---- Phase A: L0 GEMM (K=160) ----
#pragma unroll
        for (int m = 0; m < 5; ++m)
#pragma unroll
            for (int nt = 0; nt < 2; ++nt) {
                int row = nt * 16 + l15;
                int byte = 41984 + row * 2560 + (dirw * 640 + jj[m] * 4) * 2;
                byte ^= (row & 7) << 4;
                f16x4v bz = *(const f16x4v*)(ldsb + byte);
                acc[m][nt] = (f32x4){(float)bz[0], (float)bz[1], (float)bz[2], (float)bz[3]};
            }
#pragma unroll
        for (int ks = 0; ks < 5; ++ks) {
            f16x8 bfr[2];
#pragma unroll
            for (int nt = 0; nt < 2; ++nt) {
                int row = nt * 16 + l15;
                int byte = row * 1312 + (baseL0 + ks * 32 + lg * 8) * 2;
                byte ^= (row & 7) << 4;
                bfr[nt] = *(const f16x8*)(ldsb + byte);
            }
#pragma unroll
            for (int m = 0; m < 5; ++m) {
                f16x8 a = *(const f16x8*)(pwa + (m * 5 + ks) * 512);
                acc[m][0] = __builtin_amdgcn_mfma_f32_16x16x32_f16(a, bfr[0], acc[m][0], 0, 0, 0);
                acc[m][1] = __builtin_amdgcn_mfma_f32_16x16x32_f16(a, bfr[1], acc[m][1], 0, 0, 0);
            }
        }
        __syncthreads();
        // ---- Phase B: act0 -> h0 into tile ----
#pragma unroll
        for (int m = 0; m < 5; ++m)
#pragma unroll
            for (int nt = 0; nt < 2; ++nt) {
                float gi = sigm_(acc[m][nt][0]);
                float gf = sigm_(acc[m][nt][1]);
                float gg = tanh_(acc[m][nt][2]);
                float go = sigm_(acc[m][nt][3]);
                float c = gf * c0s[m][nt] + gi * gg;
                c0s[m][nt] = c;
                float h = go * tanh_(c);
                if (jj[m] < 150) {
                    int row = nt * 16 + l15;
                    int byte = row * 1312 + (baseL0 + jj[m]) * 2;  byte ^= (row & 7) << 4;
                    *(f16*)(ldsb + byte) = (f16)h;
                }
            }
        __syncthreads();
        // ---- Phase C: L1 GEMM (K=480) ----
#pragma unroll
        for (int m = 0; m < 5; ++m) {
            f16x4v b1 = *(const f16x4v*)(lds + 61952 + (mtb + m) * 16 + lg * 4);
            f32x4 bi = (f32x4){(float)b1[0], (float)b1[1], (float)b1[2], (float)b1[3]};
            acc[m][0] = bi;  acc[m][1] = bi;
        }
#pragma unroll
        for (int ks = 0; ks < 15; ++ks) {
            f16x8 bfr[2];
#pragma unroll
            for (int nt = 0; nt < 2; ++nt) {
                int row = nt * 16 + l15;
                int byte = row * 1312 + (baseL1 + ks * 32 + lg * 8) * 2;
                byte ^= (row & 7) << 4;
                bfr[nt] = *(const f16x8*)(ldsb + byte);
            }
#pragma unroll
            for (int m = 0; m < 5; ++m) {
                f16x8 a = *(const f16x8*)(pwc + (m * 15 + ks) * 512);
                acc[m][0] = __builtin_amdgcn_mfma_f32_16x16x32_f16(a, bfr[0], acc[m][0], 0, 0, 0);
                acc[m][1] = __builtin_amdgcn_mfma_f32_16x16x32_f16(a, bfr[1], acc[m][1], 0, 0, 0);
            }
        }
        __syncthreads();
        // ---- Phase D: act1 -> h1 into tile ----
#pragma unroll
        for (int m = 0; m < 5; ++m)
#pragma unroll
            for (int nt = 0; nt < 2; ++nt) {
                float gi = sigm_(acc[m][nt][0]);
                float gf = sigm_(acc[m][nt][1]);
                float gg = tanh_(acc[m][nt][2]);
                float go = sigm_(acc[m][nt][3]);
                float c = gf * c1s[m][nt] + gi * gg;
                c1s[m][nt] = c;
                float h = go * tanh_(c);
                if (jj[m] < 150) {
                    int row = nt * 16 + l15;
                    int byte = row * 1312 + (hw1 + jj[m]) * 2;  byte ^= (row & 7) << 4;
                    *(f16*)(ldsb + byte) = (f16)h;
                }
            }
        __syncthreads();
        // ---- Phase E: proj + output + x writeback (waves 0,1) ----
        if (w < 2) {
            f32x4 ap = (f32x4){0.f, 0.f, 0.f, 0.f};
#pragma unroll
            for (int ks = 0; ks < 20; ++ks) {
                int row = w * 16 + l15;
                int byte = row * 1312 + (ks * 32 + lg * 8) * 2;  byte ^= (row & 7) << 4;
                f16x8 bfp = *(const f16x8*)(ldsb + byte);
                f16x8 a = *(const f16x8*)(lds + 63232 + ks * 512 + l * 8);
                ap = __builtin_amdgcn_mfma_f32_16x16x32_f16(a, bfp, ap, 0, 0, 0);
            }
            if (l < 16) {
                float o0 = ap[0] + bp0, o1 = ap[1] + bp1;
                int b = b0 + w * 16 + l;
                bool live = (t < lenb);
                *(float2*)(out + ((size_t)b * 128 + t) * 2) =
                    make_float2(live ? o0 : 0.f, live ? o1 : 0.f);
                int row = w * 16 + l;
                f16x2v xv = {(f16)o0, (f16)o1};
                int byte1 = row * 1312 + 620;  byte1 ^= (row & 7) << 4;   // h0f x cols
                *(f16x2v*)(ldsb + byte1) = xv;
                int byte2 = row * 1312 + 940;  byte2 ^= (row & 7) << 4;   // h0b x cols
                *(f16x2v*)(ldsb + byte2) = xv;
            }
        }
        __syncthreads();
    }
}

extern "C" void kernel_launch(void* const* d_in, const int* in_sizes, int n_in,
                              void* d_out, int out_size, void* d_ws, size_t ws_size,
                              hipStream_t stream) {
    const float* noise = (const float*)d_in[0];
    const float* targ  = (const float*)d_in[1];
    const float* msk   = (const float*)d_in[2];
    const int*   lens  = (const int*)d_in[3];
    const float* Wih0  = (const float*)d_in[5];
    const float* Whh0  = (const float*)d_in[6];
    const float* bl0   = (const float*)d_in[7];
    const float* Wih1  = (const float*)d_in[8];
    const float* Whh1  = (const float*)d_in[9];
    const float* bl1   = (const float*)d_in[10];
    const float* Wp    = (const float*)d_in[11];
    const float* bpj   = (const float*)d_in[12];
    const float* Wit   = (const float*)d_in[13];
    const float* bit   = (const float*)d_in[14];
    const float* Wtk   = (const float*)d_in[15];
    const float* btk   = (const float*)d_in[16];

    char* ws = (char*)d_ws;
    f16*   HINIT = (f16*)(ws);
    float* CINIT = (float*)(ws + OFF_CINIT);
    f16*   BIAS0 = (f16*)(ws + OFF_BIAS0);
    f16*   PW0   = (f16*)(ws + OFF_PW0);
    f16*   PW1   = (f16*)(ws + OFF_PW1);
    f16*   PWPJ  = (f16*)(ws + OFF_PWPJ);
    f16*   B1P   = (f16*)(ws + OFF_B1P);

    hipLaunchKernelGGL(k_init,  dim3(10240), dim3(256), 0, stream,
                       noise, targ, msk, Wit, bit, Wtk, btk, HINIT, CINIT);
    hipLaunchKernelGGL(k_pack,  dim3(3245), dim3(256), 0, stream,
                       Wih0, Whh0, Wih1, Whh1, Wp, bl1, PW0, PW1, PWPJ, B1P);
    hipLaunchKernelGGL(k_bias0, dim3(10240), dim3(256), 0, stream,
                       Wih0, bl0, targ, msk, BIAS0);
    hipLaunchKernelGGL(lstm_main, dim3(64), dim3(1024), 0, stream,
                       HINIT, CINIT, BIAS0, PW0, PW1, PWPJ, B1P, bpj, lens,
                       (float*)d_out);
}

// Round 6
// 6746.590 us; speedup vs baseline: 1.5245x; 1.1861x over previous
//
#include <hip/hip_runtime.h>

// ---------------------------------------------------------------------------
// 2-layer "bidirectional" LSTM generator, B=2048, T=128, HID=150.
// R6: weight streaming via global_load_lds per-wave 6-slot LDS rings with
// counted vmcnt (cp.async analog). R0-R5 evidence: load-to-register weight
// streaming is latency-bound at ~15 GB/s/CU (MLP~4, 350-700ns fabric);
// DMA queues need no dest VGPRs -> 6KB/wave in flight -> BW-bound ingest.
// Biases folded into the GEMMs via constant tile columns (y at 152-156,
// 1.0 at 157) so no per-step bias loads and low register pressure.
// 64 WGs x 1024 thr (16 waves); wave w owns M-tiles [5w,5w+5) x 2 N-tiles.
// ---------------------------------------------------------------------------

typedef _Float16 f16;
typedef _Float16 f16x8 __attribute__((ext_vector_type(8)));
typedef _Float16 f16x2v __attribute__((ext_vector_type(2)));
typedef float    f32x4 __attribute__((ext_vector_type(4)));

#define LOG2E 1.44269504f

__device__ __forceinline__ float sigm_(float x) {
    float e = __builtin_amdgcn_exp2f(-LOG2E * x);
    return __builtin_amdgcn_rcpf(1.f + e);
}
__device__ __forceinline__ float tanh_(float x) {
    float e = __builtin_amdgcn_exp2f(2.f * LOG2E * x);
    return 1.f - 2.f * __builtin_amdgcn_rcpf(1.f + e);
}

// s_waitcnt imm: vmcnt[3:0]|[15:14], expcnt[6:4], lgkmcnt[11:8]
__device__ __forceinline__ void waitv(int n) {
    switch (n) {
        case 0: __builtin_amdgcn_s_waitcnt(0x0F70); break;
        case 1: __builtin_amdgcn_s_waitcnt(0x0F71); break;
        case 2: __builtin_amdgcn_s_waitcnt(0x0F72); break;
        case 3: __builtin_amdgcn_s_waitcnt(0x0F73); break;
        case 4: __builtin_amdgcn_s_waitcnt(0x0F74); break;
        default: __builtin_amdgcn_s_waitcnt(0x0F75); break;
    }
    __builtin_amdgcn_sched_barrier(0);
}
__device__ __forceinline__ void waitlgkm0() {
    __builtin_amdgcn_s_waitcnt(0xC07F);   // lgkmcnt(0), vmcnt(63)
    __builtin_amdgcn_sched_barrier(0);
}

typedef const __attribute__((address_space(1))) void* gas_t;
typedef __attribute__((address_space(3))) void* las_t;

__device__ __forceinline__ void dma_frag(const f16* wsrc, char* ringb, int F) {
    __builtin_amdgcn_global_load_lds((gas_t)(wsrc + (size_t)F * 512),
                                     (las_t)(ringb + (F % 6) * 1024), 16, 0, 0);
}

// ---------------- ws layout (bytes) ----------------
// HINIT [2048][640] f16; CINIT [2][2048][2][160] f32; WSTREAM [16][100][512] f16;
// PWPJ [20][64][8] f16.
#define OFF_CINIT 2621440
#define OFF_WSTR  13107200
#define OFF_PWPJ  14745600

__device__ float dot105(const float* __restrict__ noise,
                        const float* __restrict__ targ,
                        const float* __restrict__ msk,
                        const float* __restrict__ Wrow, int bb) {
    float s = 0.f;
    const float* nz = noise + (size_t)bb * 100;
#pragma unroll 4
    for (int k = 0; k < 100; ++k) s += nz[k] * Wrow[k];
    s += targ[bb*2+0]*Wrow[100] + targ[bb*2+1]*Wrow[101];
    s += msk[bb*3+0]*Wrow[102] + msk[bb*3+1]*Wrow[103] + msk[bb*3+2]*Wrow[104];
    return s;
}

// Build HINIT (tile layout [h1b | h0f,x,y,1 | h0b,x,y,1 | h1f]) and CINIT.
// Replicates torch's (B,1200).view(8,B,150) on the row-major init buffer.
__global__ void k_init(const float* __restrict__ noise, const float* __restrict__ targ,
                       const float* __restrict__ msk,
                       const float* __restrict__ Wih, const float* __restrict__ bih,
                       const float* __restrict__ Wtk, const float* __restrict__ btk,
                       f16* __restrict__ hinit, float* __restrict__ cinitp) {
    int gid = blockIdx.x * 256 + threadIdx.x;   // 2048*1280 exact
    int b = gid / 1280, c = gid % 1280;
    if (c < 640) {
        int reg = c / 160, loc = c % 160;
        float v = 0.f;
        if (loc < 150) {
            int q = (reg == 0) ? 3 : (reg == 1) ? 0 : (reg == 2) ? 1 : 2; // h1b,h0f,h0b,h1f
            size_t i = (size_t)q * 2048 * 150 + (size_t)b * 150 + loc;
            int bb = (int)(i / 1200), rr = (int)(i % 1200);
            v = dot105(noise, targ, msk, Wih + (size_t)rr * 105, bb) + bih[rr];
        } else if (reg == 1 || reg == 2) {
            if (loc < 152) {
                int o = loc - 150;
                v = dot105(noise, targ, msk, Wtk + o * 105, b) + btk[o];
            } else if (loc == 152) v = targ[b*2+0];
            else if (loc == 153)   v = targ[b*2+1];
            else if (loc <= 156)   v = msk[b*3 + (loc - 154)];
            else if (loc == 157)   v = 1.0f;
        }
        hinit[(size_t)b * 640 + c] = (f16)v;
    } else {
        int idx = c - 640;                       // layer*320 + d*160 + j
        int layer = idx / 320, r = idx % 320, d = r / 160, j = r % 160;
        float v = 0.f;
        if (j < 150) {
            int q = 4 + layer * 2 + d;
            size_t i = (size_t)q * 2048 * 150 + (size_t)b * 150 + j;
            int bb = (int)(i / 1200), rr = (int)(i % 1200);
            v = dot105(noise, targ, msk, Wih + (size_t)rr * 105, bb) + bih[rr];
        }
        cinitp[(((size_t)layer * 2048 + b) * 2 + d) * 160 + j] = v;
    }
}

// Pack weights into per-wave linear A-frag streams (consumption order) and
// proj frags. Lane l holds A[row=l&15][k=(l>>4)*8+e]. r16 -> j=jt*4+(r16>>2),
// gate g=r16&3. Biases/b_proj folded at k==157 (fwd window) / k==317 (bwd L1).
__global__ void k_pack(const float* __restrict__ Wih0, const float* __restrict__ Whh0,
                       const float* __restrict__ bl0,
                       const float* __restrict__ Wih1, const float* __restrict__ Whh1,
                       const float* __restrict__ bl1,
                       const float* __restrict__ Wp,   const float* __restrict__ bpj,
                       f16* __restrict__ wstream, f16* __restrict__ pwpj) {
    int gid = blockIdx.x * 256 + threadIdx.x;
    if (gid < 819200) {          // [w][100][64][8]
        int e = gid & 7, l = (gid >> 3) & 63;
        int f = (gid >> 9) % 100, w = gid / 51200;
        int r16 = l & 15, k8 = (l >> 4) * 8 + e;
        float v = 0.f;
        if (f < 25) {            // L0 frags: ks=f/5, m=f%5
            int ks = f / 5, m = f % 5;
            int mt = w * 5 + m, d = mt / 40, jt = mt % 40;
            int j = jt * 4 + (r16 >> 2), g = r16 & 3;
            int k = ks * 32 + k8;
            if (j < 150) {
                int R = d * 600 + g * 150 + j;
                if (k < 150)       v = Whh0[(size_t)R * 150 + k];
                else if (k < 157)  v = Wih0[(size_t)R * 7 + (k - 150)]; // x(2)+y(5)
                else if (k == 157) v = bl0[R];
            }
        } else {                 // L1 frags
            int fc = f - 25, ks = fc / 5, m = fc % 5;
            int mt = w * 5 + m, d = mt / 40, jt = mt % 40;
            int j = jt * 4 + (r16 >> 2), g = r16 & 3;
            int k = ks * 32 + k8;
            if (j < 150) {
                int R = d * 600 + g * 150 + j;
                if (d == 0) {   // fwd window [h0f,x,y,1 | h0b,... | h1f,...]
                    if (k < 150)                  v = Wih1[(size_t)R * 300 + k];
                    else if (k == 157)            v = bl1[R];
                    else if (k >= 160 && k < 310) v = Wih1[(size_t)R * 300 + (k - 10)];
                    else if (k >= 320 && k < 470) v = Whh1[(size_t)R * 150 + (k - 320)];
                } else {        // bwd window [h1b,pad | h0f,x,y,1 | h0b,...]
                    if (k < 150)                  v = Whh1[(size_t)R * 150 + k];
                    else if (k >= 160 && k < 310) v = Wih1[(size_t)R * 300 + (k - 160)];
                    else if (k == 317)            v = bl1[R];
                    else if (k >= 320 && k < 470) v = Wih1[(size_t)R * 300 + (k - 170)];
                }
            }
        }
        wstream[gid] = (f16)v;
    } else {                     // proj frags [20][64][8]
        int pg = gid - 819200;
        int e = pg & 7, l = (pg >> 3) & 63, ks = pg >> 9;
        int r16 = l & 15, k = ks * 32 + (l >> 4) * 8 + e;
        float v = 0.f;
        if (r16 < 2) {           // h1b at 0..149, b at 157, h1f at 480..629
            if (k < 150)                  v = Wp[r16 * 300 + 150 + k];
            else if (k == 157)            v = bpj[r16];
            else if (k >= 480 && k < 630) v = Wp[r16 * 300 + (k - 480)];
        }
        pwpj[pg] = (f16)v;
    }
}

// ---------------------------------------------------------------------------
// Main persistent kernel. LDS bytes: tile 0..41984 (32x1312, XOR-swizzled),
// pjl 41984..62464, rings 62464 + w*6144 (6 slots x 1KB per wave).
// Frags per step per wave: 0..24 = L0 (ksx5+m), 25..99 = L1. Ring slot F%6.
// Prologue DMAs issued in the PREVIOUS phase; __syncthreads' vmcnt(0) drain
// is the landing fence. In-loop: waitv(min(5,last-F)) before read,
// lgkmcnt(0)+sched_barrier before slot-reuse DMA issue.
// ---------------------------------------------------------------------------
__global__ __launch_bounds__(1024) void lstm_main(
    const f16* __restrict__ hinit, const float* __restrict__ cinit,
    const f16* __restrict__ wstream, const f16* __restrict__ pwpj,
    const int* __restrict__ lengths, float* __restrict__ out) {
    __shared__ f16 lds[80384];
    char* ldsb = (char*)lds;
    const int tid = threadIdx.x;
    const int w = tid >> 6, l = tid & 63;
    const int b0 = blockIdx.x * 32;
    const int l15 = l & 15, lg = l >> 4;
    const int dirw = w >> 3;

    // ---- stage LDS ----
    for (int it = tid; it < 32 * 80; it += 1024) {        // tile <- HINIT
        int row = it / 80, c8 = (it % 80) * 8;
        f16x8 v = *(const f16x8*)(hinit + (size_t)(b0 + row) * 640 + c8);
        int byte = row * 1312 + c8 * 2;  byte ^= (row & 7) << 4;
        *(f16x8*)(ldsb + byte) = v;
    }
    for (int it = tid; it < 1280; it += 1024)             // pjl
        *(f16x8*)(lds + 20992 + it * 8) = *(const f16x8*)(pwpj + it * 8);

    int jj[5];
#pragma unroll
    for (int m = 0; m < 5; ++m) jj[m] = ((w * 5 + m) % 40) * 4 + lg;

    float c0s[5][2], c1s[5][2];
#pragma unroll
    for (int m = 0; m < 5; ++m)
#pragma unroll
        for (int nt = 0; nt < 2; ++nt) {
            int b = b0 + nt * 16 + l15;
            c0s[m][nt] = cinit[((size_t)b * 2 + dirw) * 160 + jj[m]];
            c1s[m][nt] = cinit[(((size_t)2048 + b) * 2 + dirw) * 160 + jj[m]];
        }

    int lenb = 0;
    if (w < 2 && l < 16) lenb = lengths[b0 + w * 16 + l];

    const int baseL0 = 160 + dirw * 160;
    const int baseL1 = dirw ? 0 : 160;
    const int hw1    = dirw ? 0 : 480;
    const f16* wsrc = wstream + (size_t)w * 51200 + l * 8;  // per-lane stream base
    char* ringb = ldsb + 62464 + w * 6144;

    // initial prologue: frags 0..5 (drained by the staging barrier)
#pragma unroll
    for (int F = 0; F < 6; ++F) dma_frag(wsrc, ringb, F);

    __syncthreads();

#pragma unroll 1
    for (int t = 0; t < 128; ++t) {
        f32x4 acc[5][2];
        // ---- Phase A: L0 GEMM (K=160), frags 0..24 ----
#pragma unroll
        for (int m = 0; m < 5; ++m) {
            acc[m][0] = (f32x4){0.f, 0.f, 0.f, 0.f};
            acc[m][1] = (f32x4){0.f, 0.f, 0.f, 0.f};
        }
#pragma unroll
        for (int ks = 0; ks < 5; ++ks) {
            f16x8 bfr[2];
#pragma unroll
            for (int nt = 0; nt < 2; ++nt) {
                int row = nt * 16 + l15;
                int byte = row * 1312 + (baseL0 + ks * 32 + lg * 8) * 2;
                byte ^= (row & 7) << 4;
                bfr[nt] = *(const f16x8*)(ldsb + byte);
            }
#pragma unroll
            for (int m = 0; m < 5; ++m) {
                const int F = ks * 5 + m;
                if (F >= 6) waitv(24 - F < 5 ? 24 - F : 5);
                f16x8 a = *(const f16x8*)(ringb + (F % 6) * 1024 + l * 16);
                if (F + 6 < 25) { waitlgkm0(); dma_frag(wsrc, ringb, F + 6); }
                acc[m][0] = __builtin_amdgcn_mfma_f32_16x16x32_f16(a, bfr[0], acc[m][0], 0, 0, 0);
                acc[m][1] = __builtin_amdgcn_mfma_f32_16x16x32_f16(a, bfr[1], acc[m][1], 0, 0, 0);
            }
        }
        __syncthreads();
        // ---- Phase B: C-prologue DMAs (frags 25..30) + act0 -> h0 ----
        waitlgkm0();
#pragma unroll
        for (int F = 25; F < 31; ++F) dma_frag(wsrc, ringb, F);
#pragma unroll
        for (int m = 0; m < 5; ++m)
#pragma unroll
            for (int nt = 0; nt < 2; ++nt) {
                float gi = sigm_(acc[m][nt][0]);
                float gf = sigm_(acc[m][nt][1]);
                float gg = tanh_(acc[m][nt][2]);
                float go = sigm_(acc[m][nt][3]);
                float c = gf * c0s[m][nt] + gi * gg;
                c0s[m][nt] = c;
                float h = go * tanh_(c);
                if (jj[m] < 150) {
                    int row = nt * 16 + l15;
                    int byte = row * 1312 + (baseL0 + jj[m]) * 2;  byte ^= (row & 7) << 4;
                    *(f16*)(ldsb + byte) = (f16)h;
                }
            }
        __syncthreads();
        // ---- Phase C: L1 GEMM (K=480), frags 25..99 ----
#pragma unroll
        for (int m = 0; m < 5; ++m) {
            acc[m][0] = (f32x4){0.f, 0.f, 0.f, 0.f};
            acc[m][1] = (f32x4){0.f, 0.f, 0.f, 0.f};
        }
#pragma unroll
        for (int ks = 0; ks < 15; ++ks) {
            f16x8 bfr[2];
#pragma unroll
            for (int nt = 0; nt < 2; ++nt) {
                int row = nt * 16 + l15;
                int byte = row * 1312 + (baseL1 + ks * 32 + lg * 8) * 2;
                byte ^= (row & 7) << 4;
                bfr[nt] = *(const f16x8*)(ldsb + byte);
            }
#pragma unroll
            for (int m = 0; m < 5; ++m) {
                const int F = 25 + ks * 5 + m;
                if (F >= 31) waitv(99 - F < 5 ? 99 - F : 5);
                f16x8 a = *(const f16x8*)(ringb + (F % 6) * 1024 + l * 16);
                if (F + 6 < 100) { waitlgkm0(); dma_frag(wsrc, ringb, F + 6); }
                acc[m][0] = __builtin_amdgcn_mfma_f32_16x16x32_f16(a, bfr[0], acc[m][0], 0, 0, 0);
                acc[m][1] = __builtin_amdgcn_mfma_f32_16x16x32_f16(a, bfr[1], acc[m][1], 0, 0, 0);
            }
        }
        __syncthreads();
        // ---- Phase D: next-A prologue DMAs (frags 0..5) + act1 -> h1 ----
        waitlgkm0();
#pragma unroll
        for (int F = 0; F < 6; ++F) dma_frag(wsrc, ringb, F);
#pragma unroll
        for (int m = 0; m < 5; ++m)
#pragma unroll
            for (int nt = 0; nt < 2; ++nt) {
                float gi = sigm_(acc[m][nt][0]);
                float gf = sigm_(acc[m][nt][1]);
                float gg = tanh_(acc[m][nt][2]);
                float go = sigm_(acc[m][nt][3]);
                float c = gf * c1s[m][nt] + gi * gg;
                c1s[m][nt] = c;
                float h = go * tanh_(c);
                if (jj[m] < 150) {
                    int row = nt * 16 + l15;
                    int byte = row * 1312 + (hw1 + jj[m]) * 2;  byte ^= (row & 7) << 4;
                    *(f16*)(ldsb + byte) = (f16)h;
                }
            }
        __syncthreads();
        // ---- Phase E: proj (b_proj folded at k=157) + out + x writeback ----
        if (w < 2) {
            f32x4 ap = (f32x4){0.f, 0.f, 0.f, 0.f};
#pragma unroll
            for (int ks = 0; ks < 20; ++ks) {
                int row = w * 16 + l15;
                int byte = row * 1312 + (ks * 32 + lg * 8) * 2;  byte ^= (row & 7) << 4;
                f16x8 bfp = *(const f16x8*)(ldsb + byte);
                f16x8 a = *(const f16x8*)(lds + 20992 + ks * 512 + l * 8);
                ap = __builtin_amdgcn_mfma_f32_16x16x32_f16(a, bfp, ap, 0, 0, 0);
            }
            if (l < 16) {
                float o0 = ap[0], o1 = ap[1];
                int b = b0 + w * 16 + l;
                bool live = (t < lenb);
                *(float2*)(out + ((size_t)b * 128 + t) * 2) =
                    make_float2(live ? o0 : 0.f, live ? o1 : 0.f);
                int row = w * 16 + l;
                f16x2v xv = {(f16)o0, (f16)o1};
                int byte1 = row * 1312 + 620;  byte1 ^= (row & 7) << 4;   // h0f x cols
                *(f16x2v*)(ldsb + byte1) = xv;
                int byte2 = row * 1312 + 940;  byte2 ^= (row & 7) << 4;   // h0b x cols
                *(f16x2v*)(ldsb + byte2) = xv;
            }
        }
        __syncthreads();
    }
}

extern "C" void kernel_launch(void* const* d_in, const int* in_sizes, int n_in,
                              void* d_out, int out_size, void* d_ws, size_t ws_size,
                              hipStream_t stream) {
    const float* noise = (const float*)d_in[0];
    const float* targ  = (const float*)d_in[1];
    const float* msk   = (const float*)d_in[2];
    const int*   lens  = (const int*)d_in[3];
    const float* Wih0  = (const float*)d_in[5];
    const float* Whh0  = (const float*)d_in[6];
    const float* bl0   = (const float*)d_in[7];
    const float* Wih1  = (const float*)d_in[8];
    const float* Whh1  = (const float*)d_in[9];
    const float* bl1   = (const float*)d_in[10];
    const float* Wp    = (const float*)d_in[11];
    const float* bpj   = (const float*)d_in[12];
    const float* Wit   = (const float*)d_in[13];
    const float* bit   = (const float*)d_in[14];
    const float* Wtk   = (const float*)d_in[15];
    const float* btk   = (const float*)d_in[16];

    char* ws = (char*)d_ws;
    f16*   HINIT = (f16*)(ws);
    float* CINIT = (float*)(ws + OFF_CINIT);
    f16*   WSTR  = (f16*)(ws + OFF_WSTR);
    f16*   PWPJ  = (f16*)(ws + OFF_PWPJ);

    hipLaunchKernelGGL(k_init,  dim3(10240), dim3(256), 0, stream,
                       noise, targ, msk, Wit, bit, Wtk, btk, HINIT, CINIT);
    hipLaunchKernelGGL(k_pack,  dim3(3240), dim3(256), 0, stream,
                       Wih0, Whh0, bl0, Wih1, Whh1, bl1, Wp, bpj, WSTR, PWPJ);
    hipLaunchKernelGGL(lstm_main, dim3(64), dim3(1024), 0, stream,
                       HINIT, CINIT, WSTR, PWPJ, lens, (float*)d_out);
}